// Round 11
// baseline (642.192 us; speedup 1.0000x reference)
//
#include <hip/hip_runtime.h>
#include <stdint.h>
#include <math.h>

#define B_N 65536
#define H_N 768
#define V_N 512
#define D_N 1280
#define E_N 8
#define N1  256
#define N2  128

#define W1E (E_N*D_N*N1)   // 2621440
#define W2E (E_N*N1*N2)    // 262144
#define TRE (24*16*512)    // 196608  text router W1 tiles
#define VRE (16*16*512)    // 131072  video router W1 tiles

#define DELTA    1e-2f
#define FLAG_CAP 8192

typedef __attribute__((ext_vector_type(8))) short bf16x8;
typedef __attribute__((ext_vector_type(4))) float f32x4;

__device__ __forceinline__ unsigned short f2bf(float f){
  union{float f;uint32_t u;}v; v.f=f;
  uint32_t r = v.u + 0x7FFFu + ((v.u>>16)&1u);
  return (unsigned short)(r>>16);
}
__device__ __forceinline__ float bf2f(unsigned short s){
  union{uint32_t u; float f;}v; v.u = ((uint32_t)s)<<16; return v.f;
}
__device__ __forceinline__ void glds16(const unsigned short* g, unsigned short* l){
  __builtin_amdgcn_global_load_lds(
      (const __attribute__((address_space(1))) void*)g,
      (__attribute__((address_space(3))) void*)l, 16, 0, 0);
}

// ---------------------------------------------------------------------------
// K0: convert expert weights + router W1 (hi/lo split) to MFMA-fragment tiles.
// ---------------------------------------------------------------------------
__global__ void convert_weights(const float* __restrict__ w1,
                                const float* __restrict__ w2,
                                const float* __restrict__ tw1,
                                const float* __restrict__ vw1,
                                unsigned short* __restrict__ w1b,
                                unsigned short* __restrict__ w2b,
                                unsigned short* __restrict__ t_hi,
                                unsigned short* __restrict__ t_lo,
                                unsigned short* __restrict__ v_hi,
                                unsigned short* __restrict__ v_lo,
                                int* __restrict__ counters){
  int i = blockIdx.x*256 + threadIdx.x;
  if (i < 16) counters[i] = 0;   // [0]=flag count, [8..15]=bucket totals
  if (i < W1E){
    int tile = i >> 9, r = i & 511;
    int l = r >> 3, j = r & 7;
    int gt = tile & 15, t2 = tile >> 4;
    int ks = t2 % 40, e = t2 / 40;
    int k = ks*32 + 8*(l>>4) + j;
    int n = gt*16 + (l&15);
    w1b[i] = f2bf(w1[((size_t)e*D_N + k)*N1 + n]);
    return;
  }
  i -= W1E;
  if (i < W2E){
    int tile = i >> 9, r = i & 511;
    int l = r >> 3, j = r & 7;
    int ft = tile & 7, t2 = tile >> 3;
    int ks = t2 & 7, e = t2 >> 3;
    int k = ks*32 + 8*(l>>4) + j;
    int f = ft*16 + (l&15);
    w2b[i] = f2bf(w2[((size_t)e*N1 + k)*N2 + f]);
    return;
  }
  i -= W2E;
  if (i < TRE){
    int tile = i >> 9, r = i & 511;
    int l = r >> 3, j = r & 7;
    int gt = tile & 15, ks = tile >> 4;
    int k = ks*32 + 8*(l>>4) + j;
    int n = gt*16 + (l&15);
    float x = tw1[(size_t)k*N1 + n];
    unsigned short h = f2bf(x);
    t_hi[i] = h;
    t_lo[i] = f2bf(x - bf2f(h));
    return;
  }
  i -= TRE;
  if (i < VRE){
    int tile = i >> 9, r = i & 511;
    int l = r >> 3, j = r & 7;
    int gt = tile & 15, ks = tile >> 4;
    int k = ks*32 + 8*(l>>4) + j;
    int n = gt*16 + (l&15);
    float x = vw1[(size_t)k*N1 + n];
    unsigned short h = f2bf(x);
    v_hi[i] = h;
    v_lo[i] = f2bf(x - bf2f(h));
  }
}

// ---------------------------------------------------------------------------
// R1: MFMA router, 2-TERM split: L ~= x_hi*(W_hi + W_lo) (= x_hi * W exactly).
// Dropped x_lo*W term has logit-error rms ~1e-3; near-tie rows (gap23 <
// DELTA=1e-2, ~10 sigma) are flagged for exact f64 recheck. x_lo is no longer
// computed or staged (halves A-LDS traffic + staging VALU; MFMA 24->16/step).
// Also writes bf16 'combined' rows (consumed by expert_sparse<1>).
// ---------------------------------------------------------------------------
__global__ __launch_bounds__(512,4) void router_mfma(
    const float* __restrict__ text, const float* __restrict__ video,
    const unsigned short* __restrict__ t_hi, const unsigned short* __restrict__ t_lo,
    const unsigned short* __restrict__ v_hi, const unsigned short* __restrict__ v_lo,
    const float* __restrict__ tb1, const float* __restrict__ tw2, const float* __restrict__ tb2,
    const float* __restrict__ vb1, const float* __restrict__ vw2, const float* __restrict__ vb2,
    int* __restrict__ selIdx, float2* __restrict__ selW,
    int* __restrict__ flags, int* __restrict__ counters,
    unsigned short* __restrict__ comb, int writeComb)
{
  __shared__ union {
    unsigned short a[2*2560];     // hi A double-buffer (lo no longer staged)
    float h[64*264];
  } s;
  __shared__ float W2s[256*8];

  const int tid = threadIdx.x;
  const int rt = blockIdx.x >> 10;
  const int r0 = (blockIdx.x & 1023) * 64;
  const float* X = rt ? video : text;
  const unsigned short* Whi = rt ? v_hi : t_hi;
  const unsigned short* Wlo = rt ? v_lo : t_lo;
  const float* b1 = rt ? vb1 : tb1;
  const float* W2 = rt ? vw2 : tw2;
  const float* b2 = rt ? vb2 : tb2;
  const int K  = rt ? V_N : H_N;
  const int NK = K >> 5;
  const int cbase = rt ? H_N : 0;

  const int w = tid >> 6, l = tid & 63;
  const int mw = w & 1, nw = w >> 1;
  const int srow = tid >> 3, skq = (tid & 7) * 4;

  for (int i = tid; i < 2048; i += 512) W2s[i] = W2[i];

  f32x4 acc[2][4];
#pragma unroll
  for (int a=0;a<2;a++)
#pragma unroll
    for (int b=0;b<4;b++) acc[a][b] = (f32x4){0.f,0.f,0.f,0.f};

  const float* xrow = X + (size_t)(r0 + srow)*K + skq;
  float4 areg = *(const float4*)xrow;

  for (int ks = 0; ks < NK; ++ks){
    {
      unsigned short* dhi = s.a + (ks&1)*2560 + srow*40 + skq;
      ushort4 uh;
      uh.x = f2bf(areg.x);
      uh.y = f2bf(areg.y);
      uh.z = f2bf(areg.z);
      uh.w = f2bf(areg.w);
      *(ushort4*)dhi = uh;
      if (writeComb)
        *(ushort4*)(comb + (size_t)(r0+srow)*D_N + cbase + ks*32 + skq) = uh;
    }
    if (ks + 1 < NK) areg = *(const float4*)(xrow + (ks+1)*32);
    __syncthreads();

    bf16x8 bh[4], bl[4];
#pragma unroll
    for (int nt=0;nt<4;nt++){
      size_t off = (size_t)(ks*16 + nw*4 + nt)*512 + l*8;
      bh[nt] = *(const bf16x8*)(Whi + off);
      bl[nt] = *(const bf16x8*)(Wlo + off);
    }
    bf16x8 ah[2];
    const unsigned short* ahi = s.a + (ks&1)*2560;
#pragma unroll
    for (int mt=0;mt<2;mt++){
      int ro = (mw*32 + mt*16 + (l&15))*40 + 8*(l>>4);
      ah[mt] = *(const bf16x8*)(ahi + ro);
    }
#pragma unroll
    for (int mt=0;mt<2;mt++)
#pragma unroll
      for (int nt=0;nt<4;nt++){
        acc[mt][nt] = __builtin_amdgcn_mfma_f32_16x16x32_bf16(ah[mt], bh[nt], acc[mt][nt], 0,0,0);
        acc[mt][nt] = __builtin_amdgcn_mfma_f32_16x16x32_bf16(ah[mt], bl[nt], acc[mt][nt], 0,0,0);
      }
    __syncthreads();   // ah reads done before next-iter staging overwrites buf
  }

#pragma unroll
  for (int mt=0;mt<2;mt++){
#pragma unroll
    for (int nt=0;nt<4;nt++){
      int n = nw*64 + nt*16 + (l&15);
      float b1v = b1[n];
#pragma unroll
      for (int i=0;i<4;i++){
        int row = mw*32 + mt*16 + (l>>4)*4 + i;
        float v = acc[mt][nt][i] + b1v;
        s.h[row*264 + n] = v > 0.f ? v : 0.f;
      }
    }
  }
  __syncthreads();

  {
    const int r = tid >> 3, j = tid & 7;
    float part[8];
#pragma unroll
    for (int e=0;e<8;e++) part[e] = 0.f;
    for (int q=0;q<32;q++){
      int n = j + 8*q;
      float hv = s.h[r*264 + n];
#pragma unroll
      for (int e=0;e<8;e++) part[e] += hv * W2s[n*8 + e];
    }
#pragma unroll
    for (int m=1;m<=4;m<<=1)
#pragma unroll
      for (int e=0;e<8;e++) part[e] += __shfl_xor(part[e], m);

    if (j == 0){
      int row = r0 + r;
      float L[8];
#pragma unroll
      for (int e=0;e<8;e++) L[e] = part[e] + b2[e];
      int i0 = 0; float v0 = L[0];
#pragma unroll
      for (int e=1;e<8;e++) if (L[e] > v0){ v0 = L[e]; i0 = e; }
      int i1 = -1; float v1 = -1e30f;
#pragma unroll
      for (int e=0;e<8;e++) if (e != i0 && L[e] > v1){ v1 = L[e]; i1 = e; }
      float v2 = -1e30f;
#pragma unroll
      for (int e=0;e<8;e++) if (e != i0 && e != i1 && L[e] > v2) v2 = L[e];
      if (v1 - v2 < DELTA){
        int idx = atomicAdd(&counters[0], 1);
        if (idx < FLAG_CAP) flags[idx] = (rt<<16) | row;
      }
      float e1 = expf(v1 - v0);
      float invd = 1.f/(1.f + e1);
      selIdx[rt*B_N + row] = i0 | (i1 << 8);
      selW[rt*B_N + row] = make_float2(invd, e1*invd);
    }
  }
}

// ---------------------------------------------------------------------------
// R2: exact f64 router for flagged near-tie rows -> overwrite selIdx/selW.
// ---------------------------------------------------------------------------
__global__ __launch_bounds__(256) void router_exact(
    const float* __restrict__ text, const float* __restrict__ video,
    const float* __restrict__ tw1, const float* __restrict__ tb1,
    const float* __restrict__ tw2, const float* __restrict__ tb2,
    const float* __restrict__ vw1, const float* __restrict__ vb1,
    const float* __restrict__ vw2, const float* __restrict__ vb2,
    int* __restrict__ selIdx, float2* __restrict__ selW,
    const int* __restrict__ flags, const int* __restrict__ counters)
{
  int nf = counters[0]; if (nf > FLAG_CAP) nf = FLAG_CAP;
  if ((int)blockIdx.x >= nf) return;
  int code = flags[blockIdx.x];
  int rt = code >> 16, row = code & 0xFFFF;
  const float* X  = rt ? video : text;
  const float* W1 = rt ? vw1 : tw1;
  const float* b1 = rt ? vb1 : tb1;
  const float* W2 = rt ? vw2 : tw2;
  const float* b2 = rt ? vb2 : tb2;
  const int K = rt ? V_N : H_N;

  __shared__ float xs[H_N];
  __shared__ double red[4][8];
  const int tid = threadIdx.x;
  for (int k = tid; k < K; k += 256) xs[k] = X[(size_t)row*K + k];
  __syncthreads();

  double sAcc = 0.0;
  for (int k = 0; k < K; ++k)
    sAcc += (double)xs[k] * (double)W1[(size_t)k*N1 + tid];
  sAcc += (double)b1[tid];
  double h = sAcc > 0.0 ? sAcc : 0.0;

  double p[8];
#pragma unroll
  for (int e=0;e<8;e++) p[e] = h * (double)W2[tid*8 + e];
#pragma unroll
  for (int m=1;m<=32;m<<=1)
#pragma unroll
    for (int e=0;e<8;e++) p[e] += __shfl_xor(p[e], m);
  if ((tid & 63) == 0){
#pragma unroll
    for (int e=0;e<8;e++) red[tid>>6][e] = p[e];
  }
  __syncthreads();
  if (tid == 0){
    double L[8];
#pragma unroll
    for (int e=0;e<8;e++) L[e] = red[0][e]+red[1][e]+red[2][e]+red[3][e] + (double)b2[e];
    int i0 = 0; double v0 = L[0];
#pragma unroll
    for (int e=1;e<8;e++) if (L[e] > v0){ v0 = L[e]; i0 = e; }
    int i1 = -1; double v1 = -1e300;
#pragma unroll
    for (int e=0;e<8;e++) if (e != i0 && L[e] > v1){ v1 = L[e]; i1 = e; }
    double e1 = exp(v1 - v0);
    double invd = 1.0/(1.0 + e1);
    selIdx[rt*B_N + row] = i0 | (i1 << 8);
    selW[rt*B_N + row] = make_float2((float)invd, (float)(e1*invd));
  }
}

// ---------------------------------------------------------------------------
// Ordered bucketing (deterministic, row-ascending buckets).
// ---------------------------------------------------------------------------
__device__ __forceinline__ int sel_mask(const int* selIdx, int row){
  int st = selIdx[row], sv = selIdx[B_N + row];
  return (1<<(st&7)) | (1<<((st>>8)&7)) | (1<<(sv&7)) | (1<<((sv>>8)&7));
}

__global__ __launch_bounds__(256) void bucket_count(
    const int* __restrict__ selIdx, int* __restrict__ cnt)
{
  __shared__ int lcnt[8];
  const int tid = threadIdx.x;
  if (tid < 8) lcnt[tid] = 0;
  __syncthreads();
  int mask = sel_mask(selIdx, blockIdx.x*256 + tid);
#pragma unroll
  for (int e=0;e<8;e++) if ((mask>>e)&1) atomicAdd(&lcnt[e], 1);
  __syncthreads();
  if (tid < 8) cnt[blockIdx.x*8 + tid] = lcnt[tid];
}

__global__ __launch_bounds__(256) void bucket_scan(
    const int* __restrict__ cnt, int* __restrict__ base, int* __restrict__ counters)
{
  __shared__ int s[256];
  const int tid = threadIdx.x;
  for (int e=0;e<8;e++){
    int v = cnt[tid*8 + e];
    s[tid] = v; __syncthreads();
    for (int o=1;o<256;o<<=1){
      int t = (tid >= o) ? s[tid-o] : 0;
      __syncthreads();
      s[tid] += t;
      __syncthreads();
    }
    base[tid*8 + e] = s[tid] - v;
    if (tid == 255) counters[8+e] = s[255];
    __syncthreads();
  }
}

__global__ __launch_bounds__(256) void bucket_fill(
    const int* __restrict__ selIdx, const int* __restrict__ base,
    int* __restrict__ bucket)
{
  __shared__ int wtot[4][8], wexcl[4][8];
  const int tid = threadIdx.x;
  const int w = tid >> 6;
  const unsigned long long lt = (1ULL << (tid & 63)) - 1ULL;
  const int row = blockIdx.x*256 + tid;
  int mask = sel_mask(selIdx, row);
  int rank[8];
#pragma unroll
  for (int e=0;e<8;e++){
    unsigned long long b = __ballot((mask>>e)&1);
    rank[e] = (int)__popcll(b & lt);
    if ((tid & 63) == 0) wtot[w][e] = (int)__popcll(b);
  }
  __syncthreads();
  if (tid < 32){
    int e = tid & 7, ww = tid >> 3;
    int sum = 0;
    for (int x=0;x<ww;x++) sum += wtot[x][e];
    wexcl[ww][e] = sum;
  }
  __syncthreads();
#pragma unroll
  for (int e=0;e<8;e++)
    if ((mask>>e)&1)
      bucket[e*B_N + base[blockIdx.x*8 + e] + wexcl[w][e] + rank[e]] = row;
}

// ---------------------------------------------------------------------------
// K1: sparse expert MLP (round-10 structure, kept as equal-best).
// BF16A=1: A (gathered) + B (contiguous w1b chunk) staged per K-step via
// global_load_lds into a 24 KB buffer, double-buffered; one barrier/K-step.
// BF16A=0: round-4 f32 staged fallback.
// ---------------------------------------------------------------------------
template<int BF16A>
__global__ __launch_bounds__(512,4) void expert_sparse(
    const unsigned short* __restrict__ comb,
    const float* __restrict__ text, const float* __restrict__ video,
    const unsigned short* __restrict__ w1b, const float* __restrict__ b1,
    const unsigned short* __restrict__ w2b, const float* __restrict__ b2,
    const float* __restrict__ w3, const float* __restrict__ b3,
    const int* __restrict__ bucket, const int* __restrict__ counters,
    float* __restrict__ eo)
{
  __shared__ __align__(16) unsigned short shr[32768];   // 64 KB union
  __shared__ int rl[128];

  unsigned short* As  = shr;
  unsigned short* h1s = shr;

  const int tid = threadIdx.x;
  const int e = blockIdx.x & 7;          // expert <-> XCD affinity
  const int t = blockIdx.x >> 3;
  const int n_e = counters[8 + e];
  if (t*128 >= n_e) return;

  if (tid < 128){
    int idx = t*128 + tid;
    rl[tid] = (idx < n_e) ? bucket[e*B_N + idx] : -1;
  }
  __syncthreads();

  const int w = tid >> 6, l = tid & 63;
  const int mw = w & 1, nw = w >> 1;

  f32x4 acc[4][4];
#pragma unroll
  for (int a=0;a<4;a++)
#pragma unroll
    for (int b=0;b<4;b++) acc[a][b] = (f32x4){0.f,0.f,0.f,0.f};

  const unsigned short* w1e = w1b + (size_t)e*40*16*512;

  if constexpr (BF16A){
    int rr = rl[w*16 + (l&15)]; if (rr < 0) rr = 0;
    const unsigned short* gsA = comb + (size_t)rr*D_N + 8*(l>>4);

    {
      unsigned short* b0 = As;
      glds16(gsA, b0 + w*512);
      glds16(w1e + (size_t)(0*512 + w*64 + l)*8, b0 + 4096 + (0*512 + w*64)*8);
      glds16(w1e + (size_t)(1*512 + w*64 + l)*8, b0 + 4096 + (1*512 + w*64)*8);
    }

    for (int ks = 0; ks < 40; ++ks){
      __syncthreads();
      if (ks + 1 < 40){
        unsigned short* nb = As + (((ks+1)&1) ? 12288 : 0);
        const unsigned short* srcB = w1e + (size_t)(ks+1)*8192;
        glds16(gsA + (ks+1)*32, nb + w*512);
        glds16(srcB + (size_t)(0*512 + w*64 + l)*8, nb + 4096 + (0*512 + w*64)*8);
        glds16(srcB + (size_t)(1*512 + w*64 + l)*8, nb + 4096 + (1*512 + w*64)*8);
      }
      const unsigned short* Acur = As + (ks&1)*12288;
      const unsigned short* Bcur = Acur + 4096;
      bf16x8 af[4], bf[4];
#pragma unroll
      for (int mt=0;mt<4;mt++)
        af[mt] = *(const bf16x8*)(Acur + (mw*4+mt)*512 + l*8);
#pragma unroll
      for (int nt=0;nt<4;nt++)
        bf[nt] = *(const bf16x8*)(Bcur + (nw*4+nt)*512 + l*8);
#pragma unroll
      for (int mt=0;mt<4;mt++)
#pragma unroll
        for (int nt=0;nt<4;nt++)
          acc[mt][nt] = __builtin_amdgcn_mfma_f32_16x16x32_bf16(af[mt], bf[nt], acc[mt][nt], 0,0,0);
    }
    __syncthreads();
  } else {
    const int sridx = rl[(tid>>6)*16 + (l&15)];
    const int srr = sridx < 0 ? 0 : sridx;
    const float* tb = text  + (size_t)srr*H_N + (l>>4)*8;
    const float* vb = video + (size_t)srr*V_N + (l>>4)*8;
    float4 fa0 = *(const float4*)tb;
    float4 fa1 = *(const float4*)(tb + 4);

    bf16x8 bfc[4];
#pragma unroll
    for (int nt=0;nt<4;nt++)
      bfc[nt] = *(const bf16x8*)(w1e + (size_t)(nw*4 + nt)*512 + l*8);

    for (int ks = 0; ks < 40; ++ks){
      {
        union { bf16x8 v; unsigned short u[8]; } sw;
        sw.u[0]=f2bf(fa0.x); sw.u[1]=f2bf(fa0.y); sw.u[2]=f2bf(fa0.z); sw.u[3]=f2bf(fa0.w);
        sw.u[4]=f2bf(fa1.x); sw.u[5]=f2bf(fa1.y); sw.u[6]=f2bf(fa1.z); sw.u[7]=f2bf(fa1.w);
        *(bf16x8*)(As + tid*8) = sw.v;
      }
      if (ks < 39){
        int k0 = (ks+1)*32;
        const float* p = (k0 < H_N) ? (tb + k0) : (vb + (k0 - H_N));
        fa0 = *(const float4*)p;
        fa1 = *(const float4*)(p + 4);
      }
      __syncthreads();

      bf16x8 af[4];
#pragma unroll
      for (int mt=0;mt<4;mt++)
        af[mt] = *(const bf16x8*)(As + (mw*4+mt)*512 + l*8);

      bf16x8 bfn[4];
      if (ks < 39){
#pragma unroll
        for (int nt=0;nt<4;nt++)
          bfn[nt] = *(const bf16x8*)(w1e + (size_t)((ks+1)*16 + nw*4 + nt)*512 + l*8);
      }
#pragma unroll
      for (int mt=0;mt<4;mt++)
#pragma unroll
        for (int nt=0;nt<4;nt++)
          acc[mt][nt] = __builtin_amdgcn_mfma_f32_16x16x32_bf16(af[mt], bfc[nt], acc[mt][nt], 0,0,0);
      if (ks < 39){
#pragma unroll
        for (int nt=0;nt<4;nt++) bfc[nt] = bfn[nt];
      }
      __syncthreads();
    }
  }

  // epilogue 1: h1 = relu(acc + b1) -> h1s fragment tiles (GEMM2 A-operand)
#pragma unroll
  for (int mt=0;mt<4;mt++){
#pragma unroll
    for (int nt=0;nt<4;nt++){
      int n = nw*64 + nt*16 + (l&15);
      float b1v = b1[e*N1 + n];
      int tile = (mw*4+mt)*8 + (n>>5);
      int sub  = 16*((n>>3)&3);
      int jj   = n & 7;
#pragma unroll
      for (int i=0;i<4;i++){
        int r15 = (l>>4)*4 + i;
        float v = acc[mt][nt][i] + b1v;
        v = v > 0.f ? v : 0.f;
        h1s[tile*512 + (r15 + sub)*8 + jj] = f2bf(v);
      }
    }
  }
  __syncthreads();

  // GEMM2: 128x128, K=256 from h1s frag tiles; B (w2b tiles) from global.
  f32x4 acc2[4][2];
#pragma unroll
  for (int a=0;a<4;a++)
#pragma unroll
    for (int b=0;b<2;b++) acc2[a][b] = (f32x4){0.f,0.f,0.f,0.f};
  const unsigned short* w2e = w2b + (size_t)e*8*8*512;
#pragma unroll
  for (int ks2=0; ks2<8; ++ks2){
    bf16x8 af2[4], bf2v[2];
#pragma unroll
    for (int mt=0;mt<4;mt++)
      af2[mt] = *(const bf16x8*)(h1s + ((mw*4+mt)*8 + ks2)*512 + l*8);
#pragma unroll
    for (int ft=0;ft<2;ft++)
      bf2v[ft] = *(const bf16x8*)(w2e + (size_t)(ks2*8 + nw*2 + ft)*512 + l*8);
#pragma unroll
    for (int mt=0;mt<4;mt++)
#pragma unroll
      for (int ft=0;ft<2;ft++)
        acc2[mt][ft] = __builtin_amdgcn_mfma_f32_16x16x32_bf16(af2[mt], bf2v[ft], acc2[mt][ft], 0,0,0);
  }
  __syncthreads();

  // GEMM3 in registers: h2 = relu(acc2 + b2), dot with w3, 16-lane reduce.
  {
    const float* w3e = w3 + e*N2;
    const float* b2e = b2 + e*N2;
    const int f0 = nw*32 + (l&15);
    const int f1 = f0 + 16;
    float w3v0 = w3e[f0], w3v1 = w3e[f1];
    float b2v0 = b2e[f0], b2v1 = b2e[f1];
    float* red = (float*)shr;
#pragma unroll
    for (int mt=0;mt<4;mt++){
#pragma unroll
      for (int i=0;i<4;i++){
        float h20 = acc2[mt][0][i] + b2v0; h20 = h20 > 0.f ? h20 : 0.f;
        float h21 = acc2[mt][1][i] + b2v1; h21 = h21 > 0.f ? h21 : 0.f;
        float p = h20*w3v0 + h21*w3v1;
        p += __shfl_xor(p, 1);
        p += __shfl_xor(p, 2);
        p += __shfl_xor(p, 4);
        p += __shfl_xor(p, 8);
        if ((l & 15) == 0){
          int row = mw*64 + mt*16 + (l>>4)*4 + i;
          red[row*4 + nw] = p;
        }
      }
    }
    __syncthreads();
    if (tid < 128){
      int r = rl[tid];
      if (r >= 0){
        float sum = red[tid*4+0] + red[tid*4+1] + red[tid*4+2] + red[tid*4+3] + b3[e];
        eo[(size_t)r*E_N + e] = 1.f/(1.f + expf(-sum));
      }
    }
  }
}

// ---------------------------------------------------------------------------
// AG: final aggregation out[rt*B+row] = w0*eo[i0] + w1*eo[i1].
// ---------------------------------------------------------------------------
__global__ __launch_bounds__(512) void aggregate_kernel(
    const int* __restrict__ selIdx, const float2* __restrict__ selW,
    const float* __restrict__ eo, float* __restrict__ out)
{
  int row = blockIdx.x*512 + threadIdx.x;
#pragma unroll
  for (int rt=0; rt<2; rt++){
    int s = selIdx[rt*B_N + row];
    float2 wv = selW[rt*B_N + row];
    out[(size_t)rt*B_N + row] = wv.x * eo[(size_t)row*E_N + (s&7)]
                              + wv.y * eo[(size_t)row*E_N + ((s>>8)&7)];
  }
}

// ---------------------------------------------------------------------------
extern "C" void kernel_launch(void* const* d_in, const int* in_sizes, int n_in,
                              void* d_out, int out_size, void* d_ws, size_t ws_size,
                              hipStream_t stream){
  const float* text   = (const float*)d_in[0];
  const float* video  = (const float*)d_in[1];
  const float* exp_w1 = (const float*)d_in[2];
  const float* exp_b1 = (const float*)d_in[3];
  const float* exp_w2 = (const float*)d_in[4];
  const float* exp_b2 = (const float*)d_in[5];
  const float* exp_w3 = (const float*)d_in[6];
  const float* exp_b3 = (const float*)d_in[7];
  const float* tw1 = (const float*)d_in[8];
  const float* tb1 = (const float*)d_in[9];
  const float* tw2 = (const float*)d_in[10];
  const float* tb2 = (const float*)d_in[11];
  const float* vw1 = (const float*)d_in[12];
  const float* vb1 = (const float*)d_in[13];
  const float* vw2 = (const float*)d_in[14];
  const float* vb2 = (const float*)d_in[15];
  float* out = (float*)d_out;

  // ws layout (256B-aligned chunks)
  size_t off = 0;
  auto alloc = [&](size_t bytes) -> char* {
    char* p = (char*)d_ws + off;
    off += (bytes + 255) & ~(size_t)255;
    return p;
  };
  int*    counters = (int*)   alloc(16*4);
  int*    flags    = (int*)   alloc((size_t)FLAG_CAP*4);
  int*    selIdx   = (int*)   alloc((size_t)2*B_N*4);
  float2* selW     = (float2*)alloc((size_t)2*B_N*8);
  int*    bucket   = (int*)   alloc((size_t)8*B_N*4);
  int*    cnt      = (int*)   alloc((size_t)256*8*4);
  int*    base     = (int*)   alloc((size_t)256*8*4);
  float*  eo       = (float*) alloc((size_t)B_N*E_N*4);
  unsigned short* w1b  = (unsigned short*)alloc((size_t)W1E*2);
  unsigned short* w2b  = (unsigned short*)alloc((size_t)W2E*2);
  unsigned short* t_hi = (unsigned short*)alloc((size_t)TRE*2);
  unsigned short* t_lo = (unsigned short*)alloc((size_t)TRE*2);
  unsigned short* v_hi = (unsigned short*)alloc((size_t)VRE*2);
  unsigned short* v_lo = (unsigned short*)alloc((size_t)VRE*2);
  unsigned short* comb = (unsigned short*)alloc((size_t)B_N*D_N*2);  // 160 MB
  const int useComb = (off <= ws_size) ? 1 : 0;

  convert_weights<<<12544, 256, 0, stream>>>(exp_w1, exp_w2, tw1, vw1,
                                             w1b, w2b, t_hi, t_lo, v_hi, v_lo,
                                             counters);
  router_mfma<<<2048, 512, 0, stream>>>(text, video, t_hi, t_lo, v_hi, v_lo,
                                        tb1, tw2, tb2, vb1, vw2, vb2,
                                        selIdx, selW, flags, counters,
                                        comb, useComb);
  router_exact<<<FLAG_CAP, 256, 0, stream>>>(text, video, tw1, tb1, tw2, tb2,
                                             vw1, vb1, vw2, vb2,
                                             selIdx, selW, flags, counters);
  bucket_count<<<256, 256, 0, stream>>>(selIdx, cnt);
  bucket_scan<<<1, 256, 0, stream>>>(cnt, base, counters);
  bucket_fill<<<256, 256, 0, stream>>>(selIdx, base, bucket);
  if (useComb){
    expert_sparse<1><<<4096, 512, 0, stream>>>(comb, text, video,
                                               w1b, exp_b1, w2b, exp_b2,
                                               exp_w3, exp_b3, bucket, counters, eo);
  } else {
    expert_sparse<0><<<4096, 512, 0, stream>>>(comb, text, video,
                                               w1b, exp_b1, w2b, exp_b2,
                                               exp_w3, exp_b3, bucket, counters, eo);
  }
  aggregate_kernel<<<128, 512, 0, stream>>>(selIdx, selW, eo, out);
}

// Round 12
// 635.742 us; speedup vs baseline: 1.0101x; 1.0101x over previous
//
#include <hip/hip_runtime.h>
#include <stdint.h>
#include <math.h>

#define B_N 65536
#define H_N 768
#define V_N 512
#define D_N 1280
#define E_N 8
#define N1  256
#define N2  128

#define W1E (E_N*D_N*N1)   // 2621440
#define W2E (E_N*N1*N2)    // 262144
#define TRE (24*16*512)    // 196608  text router W1 tiles
#define VRE (16*16*512)    // 131072  video router W1 tiles

#define DELTA    1e-2f
#define FLAG_CAP 8192

typedef __attribute__((ext_vector_type(8))) short bf16x8;
typedef __attribute__((ext_vector_type(4))) float f32x4;

__device__ __forceinline__ unsigned short f2bf(float f){
  union{float f;uint32_t u;}v; v.f=f;
  uint32_t r = v.u + 0x7FFFu + ((v.u>>16)&1u);
  return (unsigned short)(r>>16);
}
__device__ __forceinline__ float bf2f(unsigned short s){
  union{uint32_t u; float f;}v; v.u = ((uint32_t)s)<<16; return v.f;
}
__device__ __forceinline__ void glds16(const unsigned short* g, unsigned short* l){
  __builtin_amdgcn_global_load_lds(
      (const __attribute__((address_space(1))) void*)g,
      (__attribute__((address_space(3))) void*)l, 16, 0, 0);
}

// ---------------------------------------------------------------------------
// K0: convert expert weights + router W1 (hi/lo split) to MFMA-fragment tiles.
// ---------------------------------------------------------------------------
__global__ void convert_weights(const float* __restrict__ w1,
                                const float* __restrict__ w2,
                                const float* __restrict__ tw1,
                                const float* __restrict__ vw1,
                                unsigned short* __restrict__ w1b,
                                unsigned short* __restrict__ w2b,
                                unsigned short* __restrict__ t_hi,
                                unsigned short* __restrict__ t_lo,
                                unsigned short* __restrict__ v_hi,
                                unsigned short* __restrict__ v_lo,
                                int* __restrict__ counters){
  int i = blockIdx.x*256 + threadIdx.x;
  if (i < 16) counters[i] = 0;   // [0]=flag count, [8..15]=bucket bases
  if (i < W1E){
    int tile = i >> 9, r = i & 511;
    int l = r >> 3, j = r & 7;
    int gt = tile & 15, t2 = tile >> 4;
    int ks = t2 % 40, e = t2 / 40;
    int k = ks*32 + 8*(l>>4) + j;
    int n = gt*16 + (l&15);
    w1b[i] = f2bf(w1[((size_t)e*D_N + k)*N1 + n]);
    return;
  }
  i -= W1E;
  if (i < W2E){
    int tile = i >> 9, r = i & 511;
    int l = r >> 3, j = r & 7;
    int ft = tile & 7, t2 = tile >> 3;
    int ks = t2 & 7, e = t2 >> 3;
    int k = ks*32 + 8*(l>>4) + j;
    int f = ft*16 + (l&15);
    w2b[i] = f2bf(w2[((size_t)e*N1 + k)*N2 + f]);
    return;
  }
  i -= W2E;
  if (i < TRE){
    int tile = i >> 9, r = i & 511;
    int l = r >> 3, j = r & 7;
    int gt = tile & 15, ks = tile >> 4;
    int k = ks*32 + 8*(l>>4) + j;
    int n = gt*16 + (l&15);
    float x = tw1[(size_t)k*N1 + n];
    unsigned short h = f2bf(x);
    t_hi[i] = h;
    t_lo[i] = f2bf(x - bf2f(h));
    return;
  }
  i -= TRE;
  if (i < VRE){
    int tile = i >> 9, r = i & 511;
    int l = r >> 3, j = r & 7;
    int gt = tile & 15, ks = tile >> 4;
    int k = ks*32 + 8*(l>>4) + j;
    int n = gt*16 + (l&15);
    float x = vw1[(size_t)k*N1 + n];
    unsigned short h = f2bf(x);
    v_hi[i] = h;
    v_lo[i] = f2bf(x - bf2f(h));
  }
}

// ---------------------------------------------------------------------------
// R1: MFMA router, 2-TERM split: L ~= x_hi*(W_hi + W_lo) (= x_hi*W exactly).
// Round-10 sync structure (ONE barrier per K-step, A dbuf) — the round-11
// tail barrier is removed. Near-tie rows (gap23 < DELTA=1e-2, ~10 sigma of
// the dropped-term error) flagged for exact f64 recheck.
// Also writes bf16 'combined' rows (consumed by expert_sparse<1>).
// ---------------------------------------------------------------------------
__global__ __launch_bounds__(512,4) void router_mfma(
    const float* __restrict__ text, const float* __restrict__ video,
    const unsigned short* __restrict__ t_hi, const unsigned short* __restrict__ t_lo,
    const unsigned short* __restrict__ v_hi, const unsigned short* __restrict__ v_lo,
    const float* __restrict__ tb1, const float* __restrict__ tw2, const float* __restrict__ tb2,
    const float* __restrict__ vb1, const float* __restrict__ vw2, const float* __restrict__ vb2,
    int* __restrict__ selIdx, float2* __restrict__ selW,
    int* __restrict__ flags, int* __restrict__ counters,
    unsigned short* __restrict__ comb, int writeComb)
{
  __shared__ union {
    unsigned short a[2*2560];     // hi A double-buffer
    float h[64*264];
  } s;
  __shared__ float W2s[256*8];

  const int tid = threadIdx.x;
  const int rt = blockIdx.x >> 10;
  const int r0 = (blockIdx.x & 1023) * 64;
  const float* X = rt ? video : text;
  const unsigned short* Whi = rt ? v_hi : t_hi;
  const unsigned short* Wlo = rt ? v_lo : t_lo;
  const float* b1 = rt ? vb1 : tb1;
  const float* W2 = rt ? vw2 : tw2;
  const float* b2 = rt ? vb2 : tb2;
  const int K  = rt ? V_N : H_N;
  const int NK = K >> 5;
  const int cbase = rt ? H_N : 0;

  const int w = tid >> 6, l = tid & 63;
  const int mw = w & 1, nw = w >> 1;
  const int srow = tid >> 3, skq = (tid & 7) * 4;

  for (int i = tid; i < 2048; i += 512) W2s[i] = W2[i];

  f32x4 acc[2][4];
#pragma unroll
  for (int a=0;a<2;a++)
#pragma unroll
    for (int b=0;b<4;b++) acc[a][b] = (f32x4){0.f,0.f,0.f,0.f};

  const float* xrow = X + (size_t)(r0 + srow)*K + skq;
  float4 areg = *(const float4*)xrow;

  for (int ks = 0; ks < NK; ++ks){
    {
      unsigned short* dhi = s.a + (ks&1)*2560 + srow*40 + skq;
      ushort4 uh;
      uh.x = f2bf(areg.x);
      uh.y = f2bf(areg.y);
      uh.z = f2bf(areg.z);
      uh.w = f2bf(areg.w);
      *(ushort4*)dhi = uh;
      if (writeComb)
        *(ushort4*)(comb + (size_t)(r0+srow)*D_N + cbase + ks*32 + skq) = uh;
    }
    if (ks + 1 < NK) areg = *(const float4*)(xrow + (ks+1)*32);
    __syncthreads();   // buf[ks&1] staged; next iter stages the OTHER buf -> no tail barrier

    bf16x8 bh[4], bl[4];
#pragma unroll
    for (int nt=0;nt<4;nt++){
      size_t off = (size_t)(ks*16 + nw*4 + nt)*512 + l*8;
      bh[nt] = *(const bf16x8*)(Whi + off);
      bl[nt] = *(const bf16x8*)(Wlo + off);
    }
    bf16x8 ah[2];
    const unsigned short* ahi = s.a + (ks&1)*2560;
#pragma unroll
    for (int mt=0;mt<2;mt++){
      int ro = (mw*32 + mt*16 + (l&15))*40 + 8*(l>>4);
      ah[mt] = *(const bf16x8*)(ahi + ro);
    }
#pragma unroll
    for (int mt=0;mt<2;mt++)
#pragma unroll
      for (int nt=0;nt<4;nt++){
        acc[mt][nt] = __builtin_amdgcn_mfma_f32_16x16x32_bf16(ah[mt], bh[nt], acc[mt][nt], 0,0,0);
        acc[mt][nt] = __builtin_amdgcn_mfma_f32_16x16x32_bf16(ah[mt], bl[nt], acc[mt][nt], 0,0,0);
      }
  }
  __syncthreads();   // all ah reads done before s.h overlays the union

#pragma unroll
  for (int mt=0;mt<2;mt++){
#pragma unroll
    for (int nt=0;nt<4;nt++){
      int n = nw*64 + nt*16 + (l&15);
      float b1v = b1[n];
#pragma unroll
      for (int i=0;i<4;i++){
        int row = mw*32 + mt*16 + (l>>4)*4 + i;
        float v = acc[mt][nt][i] + b1v;
        s.h[row*264 + n] = v > 0.f ? v : 0.f;
      }
    }
  }
  __syncthreads();

  {
    const int r = tid >> 3, j = tid & 7;
    float part[8];
#pragma unroll
    for (int e=0;e<8;e++) part[e] = 0.f;
    for (int q=0;q<32;q++){
      int n = j + 8*q;
      float hv = s.h[r*264 + n];
#pragma unroll
      for (int e=0;e<8;e++) part[e] += hv * W2s[n*8 + e];
    }
#pragma unroll
    for (int m=1;m<=4;m<<=1)
#pragma unroll
      for (int e=0;e<8;e++) part[e] += __shfl_xor(part[e], m);

    if (j == 0){
      int row = r0 + r;
      float L[8];
#pragma unroll
      for (int e=0;e<8;e++) L[e] = part[e] + b2[e];
      int i0 = 0; float v0 = L[0];
#pragma unroll
      for (int e=1;e<8;e++) if (L[e] > v0){ v0 = L[e]; i0 = e; }
      int i1 = -1; float v1 = -1e30f;
#pragma unroll
      for (int e=0;e<8;e++) if (e != i0 && L[e] > v1){ v1 = L[e]; i1 = e; }
      float v2 = -1e30f;
#pragma unroll
      for (int e=0;e<8;e++) if (e != i0 && e != i1 && L[e] > v2) v2 = L[e];
      if (v1 - v2 < DELTA){
        int idx = atomicAdd(&counters[0], 1);
        if (idx < FLAG_CAP) flags[idx] = (rt<<16) | row;
      }
      float e1 = expf(v1 - v0);
      float invd = 1.f/(1.f + e1);
      selIdx[rt*B_N + row] = i0 | (i1 << 8);
      selW[rt*B_N + row] = make_float2(invd, e1*invd);
    }
  }
}

// ---------------------------------------------------------------------------
// R2: exact f64 router for flagged near-tie rows -> overwrite selIdx/selW.
// ---------------------------------------------------------------------------
__global__ __launch_bounds__(256) void router_exact(
    const float* __restrict__ text, const float* __restrict__ video,
    const float* __restrict__ tw1, const float* __restrict__ tb1,
    const float* __restrict__ tw2, const float* __restrict__ tb2,
    const float* __restrict__ vw1, const float* __restrict__ vb1,
    const float* __restrict__ vw2, const float* __restrict__ vb2,
    int* __restrict__ selIdx, float2* __restrict__ selW,
    const int* __restrict__ flags, const int* __restrict__ counters)
{
  int nf = counters[0]; if (nf > FLAG_CAP) nf = FLAG_CAP;
  if ((int)blockIdx.x >= nf) return;
  int code = flags[blockIdx.x];
  int rt = code >> 16, row = code & 0xFFFF;
  const float* X  = rt ? video : text;
  const float* W1 = rt ? vw1 : tw1;
  const float* b1 = rt ? vb1 : tb1;
  const float* W2 = rt ? vw2 : tw2;
  const float* b2 = rt ? vb2 : tb2;
  const int K = rt ? V_N : H_N;

  __shared__ float xs[H_N];
  __shared__ double red[4][8];
  const int tid = threadIdx.x;
  for (int k = tid; k < K; k += 256) xs[k] = X[(size_t)row*K + k];
  __syncthreads();

  double sAcc = 0.0;
  for (int k = 0; k < K; ++k)
    sAcc += (double)xs[k] * (double)W1[(size_t)k*N1 + tid];
  sAcc += (double)b1[tid];
  double h = sAcc > 0.0 ? sAcc : 0.0;

  double p[8];
#pragma unroll
  for (int e=0;e<8;e++) p[e] = h * (double)W2[tid*8 + e];
#pragma unroll
  for (int m=1;m<=32;m<<=1)
#pragma unroll
    for (int e=0;e<8;e++) p[e] += __shfl_xor(p[e], m);
  if ((tid & 63) == 0){
#pragma unroll
    for (int e=0;e<8;e++) red[tid>>6][e] = p[e];
  }
  __syncthreads();
  if (tid == 0){
    double L[8];
#pragma unroll
    for (int e=0;e<8;e++) L[e] = red[0][e]+red[1][e]+red[2][e]+red[3][e] + (double)b2[e];
    int i0 = 0; double v0 = L[0];
#pragma unroll
    for (int e=1;e<8;e++) if (L[e] > v0){ v0 = L[e]; i0 = e; }
    int i1 = -1; double v1 = -1e300;
#pragma unroll
    for (int e=0;e<8;e++) if (e != i0 && L[e] > v1){ v1 = L[e]; i1 = e; }
    double e1 = exp(v1 - v0);
    double invd = 1.0/(1.0 + e1);
    selIdx[rt*B_N + row] = i0 | (i1 << 8);
    selW[rt*B_N + row] = make_float2((float)invd, (float)(e1*invd));
  }
}

// ---------------------------------------------------------------------------
// BB: build per-expert row buckets (round-6 single-kernel atomic version —
// ordered bucketing bought nothing and cost 2 launches + a serial scan).
// ---------------------------------------------------------------------------
__global__ __launch_bounds__(256) void bucket_build(
    const int* __restrict__ selIdx, int* __restrict__ bucket,
    int* __restrict__ counters)
{
  __shared__ int lcnt[8], lbase[8], lpos[8];
  const int tid = threadIdx.x;
  const int row = blockIdx.x*256 + tid;
  if (tid < 8){ lcnt[tid] = 0; lpos[tid] = 0; }
  __syncthreads();
  int st = selIdx[row], sv = selIdx[B_N + row];
  int mask = (1<<(st&7)) | (1<<((st>>8)&7)) | (1<<(sv&7)) | (1<<((sv>>8)&7));
#pragma unroll
  for (int e=0;e<8;e++) if ((mask>>e)&1) atomicAdd(&lcnt[e], 1);
  __syncthreads();
  if (tid < 8) lbase[tid] = atomicAdd(&counters[8+tid], lcnt[tid]);
  __syncthreads();
#pragma unroll
  for (int e=0;e<8;e++)
    if ((mask>>e)&1){
      int p = atomicAdd(&lpos[e], 1);
      bucket[e*B_N + lbase[e] + p] = row;
    }
}

// ---------------------------------------------------------------------------
// K1: sparse expert MLP (round-10 structure, equal-best of 5 schedules).
// BF16A=1: A (gathered) + B (contiguous w1b chunk) staged per K-step via
// global_load_lds into a 24 KB buffer, double-buffered; one barrier/K-step.
// BF16A=0: round-4 f32 staged fallback.
// ---------------------------------------------------------------------------
template<int BF16A>
__global__ __launch_bounds__(512,4) void expert_sparse(
    const unsigned short* __restrict__ comb,
    const float* __restrict__ text, const float* __restrict__ video,
    const unsigned short* __restrict__ w1b, const float* __restrict__ b1,
    const unsigned short* __restrict__ w2b, const float* __restrict__ b2,
    const float* __restrict__ w3, const float* __restrict__ b3,
    const int* __restrict__ bucket, const int* __restrict__ counters,
    float* __restrict__ eo)
{
  __shared__ __align__(16) unsigned short shr[32768];   // 64 KB union
  __shared__ int rl[128];

  unsigned short* As  = shr;
  unsigned short* h1s = shr;

  const int tid = threadIdx.x;
  const int e = blockIdx.x & 7;          // expert <-> XCD affinity
  const int t = blockIdx.x >> 3;
  const int n_e = counters[8 + e];
  if (t*128 >= n_e) return;

  if (tid < 128){
    int idx = t*128 + tid;
    rl[tid] = (idx < n_e) ? bucket[e*B_N + idx] : -1;
  }
  __syncthreads();

  const int w = tid >> 6, l = tid & 63;
  const int mw = w & 1, nw = w >> 1;

  f32x4 acc[4][4];
#pragma unroll
  for (int a=0;a<4;a++)
#pragma unroll
    for (int b=0;b<4;b++) acc[a][b] = (f32x4){0.f,0.f,0.f,0.f};

  const unsigned short* w1e = w1b + (size_t)e*40*16*512;

  if constexpr (BF16A){
    int rr = rl[w*16 + (l&15)]; if (rr < 0) rr = 0;
    const unsigned short* gsA = comb + (size_t)rr*D_N + 8*(l>>4);

    {
      unsigned short* b0 = As;
      glds16(gsA, b0 + w*512);
      glds16(w1e + (size_t)(0*512 + w*64 + l)*8, b0 + 4096 + (0*512 + w*64)*8);
      glds16(w1e + (size_t)(1*512 + w*64 + l)*8, b0 + 4096 + (1*512 + w*64)*8);
    }

    for (int ks = 0; ks < 40; ++ks){
      __syncthreads();
      if (ks + 1 < 40){
        unsigned short* nb = As + (((ks+1)&1) ? 12288 : 0);
        const unsigned short* srcB = w1e + (size_t)(ks+1)*8192;
        glds16(gsA + (ks+1)*32, nb + w*512);
        glds16(srcB + (size_t)(0*512 + w*64 + l)*8, nb + 4096 + (0*512 + w*64)*8);
        glds16(srcB + (size_t)(1*512 + w*64 + l)*8, nb + 4096 + (1*512 + w*64)*8);
      }
      const unsigned short* Acur = As + (ks&1)*12288;
      const unsigned short* Bcur = Acur + 4096;
      bf16x8 af[4], bf[4];
#pragma unroll
      for (int mt=0;mt<4;mt++)
        af[mt] = *(const bf16x8*)(Acur + (mw*4+mt)*512 + l*8);
#pragma unroll
      for (int nt=0;nt<4;nt++)
        bf[nt] = *(const bf16x8*)(Bcur + (nw*4+nt)*512 + l*8);
#pragma unroll
      for (int mt=0;mt<4;mt++)
#pragma unroll
        for (int nt=0;nt<4;nt++)
          acc[mt][nt] = __builtin_amdgcn_mfma_f32_16x16x32_bf16(af[mt], bf[nt], acc[mt][nt], 0,0,0);
    }
    __syncthreads();
  } else {
    const int sridx = rl[(tid>>6)*16 + (l&15)];
    const int srr = sridx < 0 ? 0 : sridx;
    const float* tb = text  + (size_t)srr*H_N + (l>>4)*8;
    const float* vb = video + (size_t)srr*V_N + (l>>4)*8;
    float4 fa0 = *(const float4*)tb;
    float4 fa1 = *(const float4*)(tb + 4);

    bf16x8 bfc[4];
#pragma unroll
    for (int nt=0;nt<4;nt++)
      bfc[nt] = *(const bf16x8*)(w1e + (size_t)(nw*4 + nt)*512 + l*8);

    for (int ks = 0; ks < 40; ++ks){
      {
        union { bf16x8 v; unsigned short u[8]; } sw;
        sw.u[0]=f2bf(fa0.x); sw.u[1]=f2bf(fa0.y); sw.u[2]=f2bf(fa0.z); sw.u[3]=f2bf(fa0.w);
        sw.u[4]=f2bf(fa1.x); sw.u[5]=f2bf(fa1.y); sw.u[6]=f2bf(fa1.z); sw.u[7]=f2bf(fa1.w);
        *(bf16x8*)(As + tid*8) = sw.v;
      }
      if (ks < 39){
        int k0 = (ks+1)*32;
        const float* p = (k0 < H_N) ? (tb + k0) : (vb + (k0 - H_N));
        fa0 = *(const float4*)p;
        fa1 = *(const float4*)(p + 4);
      }
      __syncthreads();

      bf16x8 af[4];
#pragma unroll
      for (int mt=0;mt<4;mt++)
        af[mt] = *(const bf16x8*)(As + (mw*4+mt)*512 + l*8);

      bf16x8 bfn[4];
      if (ks < 39){
#pragma unroll
        for (int nt=0;nt<4;nt++)
          bfn[nt] = *(const bf16x8*)(w1e + (size_t)((ks+1)*16 + nw*4 + nt)*512 + l*8);
      }
#pragma unroll
      for (int mt=0;mt<4;mt++)
#pragma unroll
        for (int nt=0;nt<4;nt++)
          acc[mt][nt] = __builtin_amdgcn_mfma_f32_16x16x32_bf16(af[mt], bfc[nt], acc[mt][nt], 0,0,0);
      if (ks < 39){
#pragma unroll
        for (int nt=0;nt<4;nt++) bfc[nt] = bfn[nt];
      }
      __syncthreads();
    }
  }

  // epilogue 1: h1 = relu(acc + b1) -> h1s fragment tiles (GEMM2 A-operand)
#pragma unroll
  for (int mt=0;mt<4;mt++){
#pragma unroll
    for (int nt=0;nt<4;nt++){
      int n = nw*64 + nt*16 + (l&15);
      float b1v = b1[e*N1 + n];
      int tile = (mw*4+mt)*8 + (n>>5);
      int sub  = 16*((n>>3)&3);
      int jj   = n & 7;
#pragma unroll
      for (int i=0;i<4;i++){
        int r15 = (l>>4)*4 + i;
        float v = acc[mt][nt][i] + b1v;
        v = v > 0.f ? v : 0.f;
        h1s[tile*512 + (r15 + sub)*8 + jj] = f2bf(v);
      }
    }
  }
  __syncthreads();

  // GEMM2: 128x128, K=256 from h1s frag tiles; B (w2b tiles) from global.
  f32x4 acc2[4][2];
#pragma unroll
  for (int a=0;a<4;a++)
#pragma unroll
    for (int b=0;b<2;b++) acc2[a][b] = (f32x4){0.f,0.f,0.f,0.f};
  const unsigned short* w2e = w2b + (size_t)e*8*8*512;
#pragma unroll
  for (int ks2=0; ks2<8; ++ks2){
    bf16x8 af2[4], bf2v[2];
#pragma unroll
    for (int mt=0;mt<4;mt++)
      af2[mt] = *(const bf16x8*)(h1s + ((mw*4+mt)*8 + ks2)*512 + l*8);
#pragma unroll
    for (int ft=0;ft<2;ft++)
      bf2v[ft] = *(const bf16x8*)(w2e + (size_t)(ks2*8 + nw*2 + ft)*512 + l*8);
#pragma unroll
    for (int mt=0;mt<4;mt++)
#pragma unroll
      for (int ft=0;ft<2;ft++)
        acc2[mt][ft] = __builtin_amdgcn_mfma_f32_16x16x32_bf16(af2[mt], bf2v[ft], acc2[mt][ft], 0,0,0);
  }
  __syncthreads();

  // GEMM3 in registers: h2 = relu(acc2 + b2), dot with w3, 16-lane reduce.
  {
    const float* w3e = w3 + e*N2;
    const float* b2e = b2 + e*N2;
    const int f0 = nw*32 + (l&15);
    const int f1 = f0 + 16;
    float w3v0 = w3e[f0], w3v1 = w3e[f1];
    float b2v0 = b2e[f0], b2v1 = b2e[f1];
    float* red = (float*)shr;
#pragma unroll
    for (int mt=0;mt<4;mt++){
#pragma unroll
      for (int i=0;i<4;i++){
        float h20 = acc2[mt][0][i] + b2v0; h20 = h20 > 0.f ? h20 : 0.f;
        float h21 = acc2[mt][1][i] + b2v1; h21 = h21 > 0.f ? h21 : 0.f;
        float p = h20*w3v0 + h21*w3v1;
        p += __shfl_xor(p, 1);
        p += __shfl_xor(p, 2);
        p += __shfl_xor(p, 4);
        p += __shfl_xor(p, 8);
        if ((l & 15) == 0){
          int row = mw*64 + mt*16 + (l>>4)*4 + i;
          red[row*4 + nw] = p;
        }
      }
    }
    __syncthreads();
    if (tid < 128){
      int r = rl[tid];
      if (r >= 0){
        float sum = red[tid*4+0] + red[tid*4+1] + red[tid*4+2] + red[tid*4+3] + b3[e];
        eo[(size_t)r*E_N + e] = 1.f/(1.f + expf(-sum));
      }
    }
  }
}

// ---------------------------------------------------------------------------
// AG: final aggregation out[rt*B+row] = w0*eo[i0] + w1*eo[i1].
// ---------------------------------------------------------------------------
__global__ __launch_bounds__(512) void aggregate_kernel(
    const int* __restrict__ selIdx, const float2* __restrict__ selW,
    const float* __restrict__ eo, float* __restrict__ out)
{
  int row = blockIdx.x*512 + threadIdx.x;
#pragma unroll
  for (int rt=0; rt<2; rt++){
    int s = selIdx[rt*B_N + row];
    float2 wv = selW[rt*B_N + row];
    out[(size_t)rt*B_N + row] = wv.x * eo[(size_t)row*E_N + (s&7)]
                              + wv.y * eo[(size_t)row*E_N + ((s>>8)&7)];
  }
}

// ---------------------------------------------------------------------------
extern "C" void kernel_launch(void* const* d_in, const int* in_sizes, int n_in,
                              void* d_out, int out_size, void* d_ws, size_t ws_size,
                              hipStream_t stream){
  const float* text   = (const float*)d_in[0];
  const float* video  = (const float*)d_in[1];
  const float* exp_w1 = (const float*)d_in[2];
  const float* exp_b1 = (const float*)d_in[3];
  const float* exp_w2 = (const float*)d_in[4];
  const float* exp_b2 = (const float*)d_in[5];
  const float* exp_w3 = (const float*)d_in[6];
  const float* exp_b3 = (const float*)d_in[7];
  const float* tw1 = (const float*)d_in[8];
  const float* tb1 = (const float*)d_in[9];
  const float* tw2 = (const float*)d_in[10];
  const float* tb2 = (const float*)d_in[11];
  const float* vw1 = (const float*)d_in[12];
  const float* vb1 = (const float*)d_in[13];
  const float* vw2 = (const float*)d_in[14];
  const float* vb2 = (const float*)d_in[15];
  float* out = (float*)d_out;

  // ws layout (256B-aligned chunks)
  size_t off = 0;
  auto alloc = [&](size_t bytes) -> char* {
    char* p = (char*)d_ws + off;
    off += (bytes + 255) & ~(size_t)255;
    return p;
  };
  int*    counters = (int*)   alloc(16*4);
  int*    flags    = (int*)   alloc((size_t)FLAG_CAP*4);
  int*    selIdx   = (int*)   alloc((size_t)2*B_N*4);
  float2* selW     = (float2*)alloc((size_t)2*B_N*8);
  int*    bucket   = (int*)   alloc((size_t)8*B_N*4);
  float*  eo       = (float*) alloc((size_t)B_N*E_N*4);
  unsigned short* w1b  = (unsigned short*)alloc((size_t)W1E*2);
  unsigned short* w2b  = (unsigned short*)alloc((size_t)W2E*2);
  unsigned short* t_hi = (unsigned short*)alloc((size_t)TRE*2);
  unsigned short* t_lo = (unsigned short*)alloc((size_t)TRE*2);
  unsigned short* v_hi = (unsigned short*)alloc((size_t)VRE*2);
  unsigned short* v_lo = (unsigned short*)alloc((size_t)VRE*2);
  unsigned short* comb = (unsigned short*)alloc((size_t)B_N*D_N*2);  // 160 MB
  const int useComb = (off <= ws_size) ? 1 : 0;

  convert_weights<<<12544, 256, 0, stream>>>(exp_w1, exp_w2, tw1, vw1,
                                             w1b, w2b, t_hi, t_lo, v_hi, v_lo,
                                             counters);
  router_mfma<<<2048, 512, 0, stream>>>(text, video, t_hi, t_lo, v_hi, v_lo,
                                        tb1, tw2, tb2, vb1, vw2, vb2,
                                        selIdx, selW, flags, counters,
                                        comb, useComb);
  router_exact<<<FLAG_CAP, 256, 0, stream>>>(text, video, tw1, tb1, tw2, tb2,
                                             vw1, vb1, vw2, vb2,
                                             selIdx, selW, flags, counters);
  bucket_build<<<256, 256, 0, stream>>>(selIdx, bucket, counters);
  if (useComb){
    expert_sparse<1><<<4096, 512, 0, stream>>>(comb, text, video,
                                               w1b, exp_b1, w2b, exp_b2,
                                               exp_w3, exp_b3, bucket, counters, eo);
  } else {
    expert_sparse<0><<<4096, 512, 0, stream>>>(comb, text, video,
                                               w1b, exp_b1, w2b, exp_b2,
                                               exp_w3, exp_b3, bucket, counters, eo);
  }
  aggregate_kernel<<<128, 512, 0, stream>>>(selIdx, selW, eo, out);
}

// Round 13
// 570.813 us; speedup vs baseline: 1.1250x; 1.1137x over previous
//
#include <hip/hip_runtime.h>
#include <stdint.h>
#include <math.h>

#define B_N 65536
#define H_N 768
#define V_N 512
#define D_N 1280
#define E_N 8
#define N1  256
#define N2  128

#define W1E (E_N*D_N*N1)   // 2621440
#define W2E (E_N*N1*N2)    // 262144
#define TRE (24*16*512)    // 196608  text router W1 tiles
#define VRE (16*16*512)    // 131072  video router W1 tiles

#define DELTA    5e-3f
#define FLAG_CAP 8192

typedef __attribute__((ext_vector_type(8))) short bf16x8;
typedef __attribute__((ext_vector_type(4))) float f32x4;

__device__ __forceinline__ unsigned short f2bf(float f){
  union{float f;uint32_t u;}v; v.f=f;
  uint32_t r = v.u + 0x7FFFu + ((v.u>>16)&1u);
  return (unsigned short)(r>>16);
}
__device__ __forceinline__ float bf2f(unsigned short s){
  union{uint32_t u; float f;}v; v.u = ((uint32_t)s)<<16; return v.f;
}
__device__ __forceinline__ void glds16(const unsigned short* g, unsigned short* l){
  __builtin_amdgcn_global_load_lds(
      (const __attribute__((address_space(1))) void*)g,
      (__attribute__((address_space(3))) void*)l, 16, 0, 0);
}

// ---------------------------------------------------------------------------
// K0: convert expert weights + router W1 (hi/lo split) to MFMA-fragment tiles.
// ---------------------------------------------------------------------------
__global__ void convert_weights(const float* __restrict__ w1,
                                const float* __restrict__ w2,
                                const float* __restrict__ tw1,
                                const float* __restrict__ vw1,
                                unsigned short* __restrict__ w1b,
                                unsigned short* __restrict__ w2b,
                                unsigned short* __restrict__ t_hi,
                                unsigned short* __restrict__ t_lo,
                                unsigned short* __restrict__ v_hi,
                                unsigned short* __restrict__ v_lo,
                                int* __restrict__ counters){
  int i = blockIdx.x*256 + threadIdx.x;
  if (i < 16) counters[i] = 0;   // [0]=flag count, [8..15]=bucket bases
  if (i < W1E){
    int tile = i >> 9, r = i & 511;
    int l = r >> 3, j = r & 7;
    int gt = tile & 15, t2 = tile >> 4;
    int ks = t2 % 40, e = t2 / 40;
    int k = ks*32 + 8*(l>>4) + j;
    int n = gt*16 + (l&15);
    w1b[i] = f2bf(w1[((size_t)e*D_N + k)*N1 + n]);
    return;
  }
  i -= W1E;
  if (i < W2E){
    int tile = i >> 9, r = i & 511;
    int l = r >> 3, j = r & 7;
    int ft = tile & 7, t2 = tile >> 3;
    int ks = t2 & 7, e = t2 >> 3;
    int k = ks*32 + 8*(l>>4) + j;
    int f = ft*16 + (l&15);
    w2b[i] = f2bf(w2[((size_t)e*N1 + k)*N2 + f]);
    return;
  }
  i -= W2E;
  if (i < TRE){
    int tile = i >> 9, r = i & 511;
    int l = r >> 3, j = r & 7;
    int gt = tile & 15, ks = tile >> 4;
    int k = ks*32 + 8*(l>>4) + j;
    int n = gt*16 + (l&15);
    float x = tw1[(size_t)k*N1 + n];
    unsigned short h = f2bf(x);
    t_hi[i] = h;
    t_lo[i] = f2bf(x - bf2f(h));
    return;
  }
  i -= TRE;
  if (i < VRE){
    int tile = i >> 9, r = i & 511;
    int l = r >> 3, j = r & 7;
    int gt = tile & 15, ks = tile >> 4;
    int k = ks*32 + 8*(l>>4) + j;
    int n = gt*16 + (l&15);
    float x = vw1[(size_t)k*N1 + n];
    unsigned short h = f2bf(x);
    v_hi[i] = h;
    v_lo[i] = f2bf(x - bf2f(h));
  }
}

// ---------------------------------------------------------------------------
// R1: MFMA router, 2-TERM split: L ~= x_hi*(W_hi + W_lo) (= x_hi*W exactly).
// One barrier per K-step, A hi-only double-buffer. Near-tie rows
// (gap23 < DELTA=5e-3 ~= 6.7 sigma of the dropped-term error) flagged for
// exact f64 recheck. Also writes bf16 'combined' rows for expert_sparse<1>.
// ---------------------------------------------------------------------------
__global__ __launch_bounds__(512,4) void router_mfma(
    const float* __restrict__ text, const float* __restrict__ video,
    const unsigned short* __restrict__ t_hi, const unsigned short* __restrict__ t_lo,
    const unsigned short* __restrict__ v_hi, const unsigned short* __restrict__ v_lo,
    const float* __restrict__ tb1, const float* __restrict__ tw2, const float* __restrict__ tb2,
    const float* __restrict__ vb1, const float* __restrict__ vw2, const float* __restrict__ vb2,
    int* __restrict__ selIdx, float2* __restrict__ selW,
    int* __restrict__ flags, int* __restrict__ counters,
    unsigned short* __restrict__ comb, int writeComb)
{
  __shared__ union {
    unsigned short a[2*2560];     // hi A double-buffer
    float h[64*264];
  } s;
  __shared__ float W2s[256*8];

  const int tid = threadIdx.x;
  const int rt = blockIdx.x >> 10;
  const int r0 = (blockIdx.x & 1023) * 64;
  const float* X = rt ? video : text;
  const unsigned short* Whi = rt ? v_hi : t_hi;
  const unsigned short* Wlo = rt ? v_lo : t_lo;
  const float* b1 = rt ? vb1 : tb1;
  const float* W2 = rt ? vw2 : tw2;
  const float* b2 = rt ? vb2 : tb2;
  const int K  = rt ? V_N : H_N;
  const int NK = K >> 5;
  const int cbase = rt ? H_N : 0;

  const int w = tid >> 6, l = tid & 63;
  const int mw = w & 1, nw = w >> 1;
  const int srow = tid >> 3, skq = (tid & 7) * 4;

  for (int i = tid; i < 2048; i += 512) W2s[i] = W2[i];

  f32x4 acc[2][4];
#pragma unroll
  for (int a=0;a<2;a++)
#pragma unroll
    for (int b=0;b<4;b++) acc[a][b] = (f32x4){0.f,0.f,0.f,0.f};

  const float* xrow = X + (size_t)(r0 + srow)*K + skq;
  float4 areg = *(const float4*)xrow;

  for (int ks = 0; ks < NK; ++ks){
    {
      unsigned short* dhi = s.a + (ks&1)*2560 + srow*40 + skq;
      ushort4 uh;
      uh.x = f2bf(areg.x);
      uh.y = f2bf(areg.y);
      uh.z = f2bf(areg.z);
      uh.w = f2bf(areg.w);
      *(ushort4*)dhi = uh;
      if (writeComb)
        *(ushort4*)(comb + (size_t)(r0+srow)*D_N + cbase + ks*32 + skq) = uh;
    }
    if (ks + 1 < NK) areg = *(const float4*)(xrow + (ks+1)*32);
    __syncthreads();   // buf[ks&1] staged; next iter stages the OTHER buf

    bf16x8 bh[4], bl[4];
#pragma unroll
    for (int nt=0;nt<4;nt++){
      size_t off = (size_t)(ks*16 + nw*4 + nt)*512 + l*8;
      bh[nt] = *(const bf16x8*)(Whi + off);
      bl[nt] = *(const bf16x8*)(Wlo + off);
    }
    bf16x8 ah[2];
    const unsigned short* ahi = s.a + (ks&1)*2560;
#pragma unroll
    for (int mt=0;mt<2;mt++){
      int ro = (mw*32 + mt*16 + (l&15))*40 + 8*(l>>4);
      ah[mt] = *(const bf16x8*)(ahi + ro);
    }
#pragma unroll
    for (int mt=0;mt<2;mt++)
#pragma unroll
      for (int nt=0;nt<4;nt++){
        acc[mt][nt] = __builtin_amdgcn_mfma_f32_16x16x32_bf16(ah[mt], bh[nt], acc[mt][nt], 0,0,0);
        acc[mt][nt] = __builtin_amdgcn_mfma_f32_16x16x32_bf16(ah[mt], bl[nt], acc[mt][nt], 0,0,0);
      }
  }
  __syncthreads();   // all ah reads done before s.h overlays the union

#pragma unroll
  for (int mt=0;mt<2;mt++){
#pragma unroll
    for (int nt=0;nt<4;nt++){
      int n = nw*64 + nt*16 + (l&15);
      float b1v = b1[n];
#pragma unroll
      for (int i=0;i<4;i++){
        int row = mw*32 + mt*16 + (l>>4)*4 + i;
        float v = acc[mt][nt][i] + b1v;
        s.h[row*264 + n] = v > 0.f ? v : 0.f;
      }
    }
  }
  __syncthreads();

  {
    const int r = tid >> 3, j = tid & 7;
    float part[8];
#pragma unroll
    for (int e=0;e<8;e++) part[e] = 0.f;
    for (int q=0;q<32;q++){
      int n = j + 8*q;
      float hv = s.h[r*264 + n];
#pragma unroll
      for (int e=0;e<8;e++) part[e] += hv * W2s[n*8 + e];
    }
#pragma unroll
    for (int m=1;m<=4;m<<=1)
#pragma unroll
      for (int e=0;e<8;e++) part[e] += __shfl_xor(part[e], m);

    if (j == 0){
      int row = r0 + r;
      float L[8];
#pragma unroll
      for (int e=0;e<8;e++) L[e] = part[e] + b2[e];
      int i0 = 0; float v0 = L[0];
#pragma unroll
      for (int e=1;e<8;e++) if (L[e] > v0){ v0 = L[e]; i0 = e; }
      int i1 = -1; float v1 = -1e30f;
#pragma unroll
      for (int e=0;e<8;e++) if (e != i0 && L[e] > v1){ v1 = L[e]; i1 = e; }
      float v2 = -1e30f;
#pragma unroll
      for (int e=0;e<8;e++) if (e != i0 && e != i1 && L[e] > v2) v2 = L[e];
      if (v1 - v2 < DELTA){
        int idx = atomicAdd(&counters[0], 1);
        if (idx < FLAG_CAP) flags[idx] = (rt<<16) | row;
      }
      float e1 = expf(v1 - v0);
      float invd = 1.f/(1.f + e1);
      selIdx[rt*B_N + row] = i0 | (i1 << 8);
      selW[rt*B_N + row] = make_float2(invd, e1*invd);
    }
  }
}

// ---------------------------------------------------------------------------
// R2: exact f64 router for flagged near-tie rows -> overwrite selIdx/selW.
// 4 independent f64 accumulators break the serial FMA chain (4x ILP).
// ---------------------------------------------------------------------------
__global__ __launch_bounds__(256) void router_exact(
    const float* __restrict__ text, const float* __restrict__ video,
    const float* __restrict__ tw1, const float* __restrict__ tb1,
    const float* __restrict__ tw2, const float* __restrict__ tb2,
    const float* __restrict__ vw1, const float* __restrict__ vb1,
    const float* __restrict__ vw2, const float* __restrict__ vb2,
    int* __restrict__ selIdx, float2* __restrict__ selW,
    const int* __restrict__ flags, const int* __restrict__ counters)
{
  int nf = counters[0]; if (nf > FLAG_CAP) nf = FLAG_CAP;
  if ((int)blockIdx.x >= nf) return;
  int code = flags[blockIdx.x];
  int rt = code >> 16, row = code & 0xFFFF;
  const float* X  = rt ? video : text;
  const float* W1 = rt ? vw1 : tw1;
  const float* b1 = rt ? vb1 : tb1;
  const float* W2 = rt ? vw2 : tw2;
  const float* b2 = rt ? vb2 : tb2;
  const int K = rt ? V_N : H_N;

  __shared__ float xs[H_N];
  __shared__ double red[4][8];
  const int tid = threadIdx.x;
  for (int k = tid; k < K; k += 256) xs[k] = X[(size_t)row*K + k];
  __syncthreads();

  double a0 = 0.0, a1 = 0.0, a2 = 0.0, a3 = 0.0;
  for (int k = 0; k < K; k += 4){
    a0 += (double)xs[k+0] * (double)W1[(size_t)(k+0)*N1 + tid];
    a1 += (double)xs[k+1] * (double)W1[(size_t)(k+1)*N1 + tid];
    a2 += (double)xs[k+2] * (double)W1[(size_t)(k+2)*N1 + tid];
    a3 += (double)xs[k+3] * (double)W1[(size_t)(k+3)*N1 + tid];
  }
  double sAcc = ((a0 + a1) + (a2 + a3)) + (double)b1[tid];
  double h = sAcc > 0.0 ? sAcc : 0.0;

  double p[8];
#pragma unroll
  for (int e=0;e<8;e++) p[e] = h * (double)W2[tid*8 + e];
#pragma unroll
  for (int m=1;m<=32;m<<=1)
#pragma unroll
    for (int e=0;e<8;e++) p[e] += __shfl_xor(p[e], m);
  if ((tid & 63) == 0){
#pragma unroll
    for (int e=0;e<8;e++) red[tid>>6][e] = p[e];
  }
  __syncthreads();
  if (tid == 0){
    double L[8];
#pragma unroll
    for (int e=0;e<8;e++) L[e] = red[0][e]+red[1][e]+red[2][e]+red[3][e] + (double)b2[e];
    int i0 = 0; double v0 = L[0];
#pragma unroll
    for (int e=1;e<8;e++) if (L[e] > v0){ v0 = L[e]; i0 = e; }
    int i1 = -1; double v1 = -1e300;
#pragma unroll
    for (int e=0;e<8;e++) if (e != i0 && L[e] > v1){ v1 = L[e]; i1 = e; }
    double e1 = exp(v1 - v0);
    double invd = 1.0/(1.0 + e1);
    selIdx[rt*B_N + row] = i0 | (i1 << 8);
    selW[rt*B_N + row] = make_float2((float)invd, (float)(e1*invd));
  }
}

// ---------------------------------------------------------------------------
// BB: build per-expert row buckets (single-kernel block-aggregated atomics).
// ---------------------------------------------------------------------------
__global__ __launch_bounds__(256) void bucket_build(
    const int* __restrict__ selIdx, int* __restrict__ bucket,
    int* __restrict__ counters)
{
  __shared__ int lcnt[8], lbase[8], lpos[8];
  const int tid = threadIdx.x;
  const int row = blockIdx.x*256 + tid;
  if (tid < 8){ lcnt[tid] = 0; lpos[tid] = 0; }
  __syncthreads();
  int st = selIdx[row], sv = selIdx[B_N + row];
  int mask = (1<<(st&7)) | (1<<((st>>8)&7)) | (1<<(sv&7)) | (1<<((sv>>8)&7));
#pragma unroll
  for (int e=0;e<8;e++) if ((mask>>e)&1) atomicAdd(&lcnt[e], 1);
  __syncthreads();
  if (tid < 8) lbase[tid] = atomicAdd(&counters[8+tid], lcnt[tid]);
  __syncthreads();
#pragma unroll
  for (int e=0;e<8;e++)
    if ((mask>>e)&1){
      int p = atomicAdd(&lpos[e], 1);
      bucket[e*B_N + lbase[e] + p] = row;
    }
}

// ---------------------------------------------------------------------------
// K1: sparse expert MLP (round-10 structure, equal-best of 5 schedules).
// BF16A=1: A (gathered) + B (contiguous w1b chunk) staged per K-step via
// global_load_lds into a 24 KB buffer, double-buffered; one barrier/K-step.
// BF16A=0: round-4 f32 staged fallback.
// ---------------------------------------------------------------------------
template<int BF16A>
__global__ __launch_bounds__(512,4) void expert_sparse(
    const unsigned short* __restrict__ comb,
    const float* __restrict__ text, const float* __restrict__ video,
    const unsigned short* __restrict__ w1b, const float* __restrict__ b1,
    const unsigned short* __restrict__ w2b, const float* __restrict__ b2,
    const float* __restrict__ w3, const float* __restrict__ b3,
    const int* __restrict__ bucket, const int* __restrict__ counters,
    float* __restrict__ eo)
{
  __shared__ __align__(16) unsigned short shr[32768];   // 64 KB union
  __shared__ int rl[128];

  unsigned short* As  = shr;
  unsigned short* h1s = shr;

  const int tid = threadIdx.x;
  const int e = blockIdx.x & 7;          // expert <-> XCD affinity
  const int t = blockIdx.x >> 3;
  const int n_e = counters[8 + e];
  if (t*128 >= n_e) return;

  if (tid < 128){
    int idx = t*128 + tid;
    rl[tid] = (idx < n_e) ? bucket[e*B_N + idx] : -1;
  }
  __syncthreads();

  const int w = tid >> 6, l = tid & 63;
  const int mw = w & 1, nw = w >> 1;

  f32x4 acc[4][4];
#pragma unroll
  for (int a=0;a<4;a++)
#pragma unroll
    for (int b=0;b<4;b++) acc[a][b] = (f32x4){0.f,0.f,0.f,0.f};

  const unsigned short* w1e = w1b + (size_t)e*40*16*512;

  if constexpr (BF16A){
    int rr = rl[w*16 + (l&15)]; if (rr < 0) rr = 0;
    const unsigned short* gsA = comb + (size_t)rr*D_N + 8*(l>>4);

    {
      unsigned short* b0 = As;
      glds16(gsA, b0 + w*512);
      glds16(w1e + (size_t)(0*512 + w*64 + l)*8, b0 + 4096 + (0*512 + w*64)*8);
      glds16(w1e + (size_t)(1*512 + w*64 + l)*8, b0 + 4096 + (1*512 + w*64)*8);
    }

    for (int ks = 0; ks < 40; ++ks){
      __syncthreads();
      if (ks + 1 < 40){
        unsigned short* nb = As + (((ks+1)&1) ? 12288 : 0);
        const unsigned short* srcB = w1e + (size_t)(ks+1)*8192;
        glds16(gsA + (ks+1)*32, nb + w*512);
        glds16(srcB + (size_t)(0*512 + w*64 + l)*8, nb + 4096 + (0*512 + w*64)*8);
        glds16(srcB + (size_t)(1*512 + w*64 + l)*8, nb + 4096 + (1*512 + w*64)*8);
      }
      const unsigned short* Acur = As + (ks&1)*12288;
      const unsigned short* Bcur = Acur + 4096;
      bf16x8 af[4], bf[4];
#pragma unroll
      for (int mt=0;mt<4;mt++)
        af[mt] = *(const bf16x8*)(Acur + (mw*4+mt)*512 + l*8);
#pragma unroll
      for (int nt=0;nt<4;nt++)
        bf[nt] = *(const bf16x8*)(Bcur + (nw*4+nt)*512 + l*8);
#pragma unroll
      for (int mt=0;mt<4;mt++)
#pragma unroll
        for (int nt=0;nt<4;nt++)
          acc[mt][nt] = __builtin_amdgcn_mfma_f32_16x16x32_bf16(af[mt], bf[nt], acc[mt][nt], 0,0,0);
    }
    __syncthreads();
  } else {
    const int sridx = rl[(tid>>6)*16 + (l&15)];
    const int srr = sridx < 0 ? 0 : sridx;
    const float* tb = text  + (size_t)srr*H_N + (l>>4)*8;
    const float* vb = video + (size_t)srr*V_N + (l>>4)*8;
    float4 fa0 = *(const float4*)tb;
    float4 fa1 = *(const float4*)(tb + 4);

    bf16x8 bfc[4];
#pragma unroll
    for (int nt=0;nt<4;nt++)
      bfc[nt] = *(const bf16x8*)(w1e + (size_t)(nw*4 + nt)*512 + l*8);

    for (int ks = 0; ks < 40; ++ks){
      {
        union { bf16x8 v; unsigned short u[8]; } sw;
        sw.u[0]=f2bf(fa0.x); sw.u[1]=f2bf(fa0.y); sw.u[2]=f2bf(fa0.z); sw.u[3]=f2bf(fa0.w);
        sw.u[4]=f2bf(fa1.x); sw.u[5]=f2bf(fa1.y); sw.u[6]=f2bf(fa1.z); sw.u[7]=f2bf(fa1.w);
        *(bf16x8*)(As + tid*8) = sw.v;
      }
      if (ks < 39){
        int k0 = (ks+1)*32;
        const float* p = (k0 < H_N) ? (tb + k0) : (vb + (k0 - H_N));
        fa0 = *(const float4*)p;
        fa1 = *(const float4*)(p + 4);
      }
      __syncthreads();

      bf16x8 af[4];
#pragma unroll
      for (int mt=0;mt<4;mt++)
        af[mt] = *(const bf16x8*)(As + (mw*4+mt)*512 + l*8);

      bf16x8 bfn[4];
      if (ks < 39){
#pragma unroll
        for (int nt=0;nt<4;nt++)
          bfn[nt] = *(const bf16x8*)(w1e + (size_t)((ks+1)*16 + nw*4 + nt)*512 + l*8);
      }
#pragma unroll
      for (int mt=0;mt<4;mt++)
#pragma unroll
        for (int nt=0;nt<4;nt++)
          acc[mt][nt] = __builtin_amdgcn_mfma_f32_16x16x32_bf16(af[mt], bfc[nt], acc[mt][nt], 0,0,0);
      if (ks < 39){
#pragma unroll
        for (int nt=0;nt<4;nt++) bfc[nt] = bfn[nt];
      }
      __syncthreads();
    }
  }

  // epilogue 1: h1 = relu(acc + b1) -> h1s fragment tiles (GEMM2 A-operand)
#pragma unroll
  for (int mt=0;mt<4;mt++){
#pragma unroll
    for (int nt=0;nt<4;nt++){
      int n = nw*64 + nt*16 + (l&15);
      float b1v = b1[e*N1 + n];
      int tile = (mw*4+mt)*8 + (n>>5);
      int sub  = 16*((n>>3)&3);
      int jj   = n & 7;
#pragma unroll
      for (int i=0;i<4;i++){
        int r15 = (l>>4)*4 + i;
        float v = acc[mt][nt][i] + b1v;
        v = v > 0.f ? v : 0.f;
        h1s[tile*512 + (r15 + sub)*8 + jj] = f2bf(v);
      }
    }
  }
  __syncthreads();

  // GEMM2: 128x128, K=256 from h1s frag tiles; B (w2b tiles) from global.
  f32x4 acc2[4][2];
#pragma unroll
  for (int a=0;a<4;a++)
#pragma unroll
    for (int b=0;b<2;b++) acc2[a][b] = (f32x4){0.f,0.f,0.f,0.f};
  const unsigned short* w2e = w2b + (size_t)e*8*8*512;
#pragma unroll
  for (int ks2=0; ks2<8; ++ks2){
    bf16x8 af2[4], bf2v[2];
#pragma unroll
    for (int mt=0;mt<4;mt++)
      af2[mt] = *(const bf16x8*)(h1s + ((mw*4+mt)*8 + ks2)*512 + l*8);
#pragma unroll
    for (int ft=0;ft<2;ft++)
      bf2v[ft] = *(const bf16x8*)(w2e + (size_t)(ks2*8 + nw*2 + ft)*512 + l*8);
#pragma unroll
    for (int mt=0;mt<4;mt++)
#pragma unroll
      for (int ft=0;ft<2;ft++)
        acc2[mt][ft] = __builtin_amdgcn_mfma_f32_16x16x32_bf16(af2[mt], bf2v[ft], acc2[mt][ft], 0,0,0);
  }
  __syncthreads();

  // GEMM3 in registers: h2 = relu(acc2 + b2), dot with w3, 16-lane reduce.
  {
    const float* w3e = w3 + e*N2;
    const float* b2e = b2 + e*N2;
    const int f0 = nw*32 + (l&15);
    const int f1 = f0 + 16;
    float w3v0 = w3e[f0], w3v1 = w3e[f1];
    float b2v0 = b2e[f0], b2v1 = b2e[f1];
    float* red = (float*)shr;
#pragma unroll
    for (int mt=0;mt<4;mt++){
#pragma unroll
      for (int i=0;i<4;i++){
        float h20 = acc2[mt][0][i] + b2v0; h20 = h20 > 0.f ? h20 : 0.f;
        float h21 = acc2[mt][1][i] + b2v1; h21 = h21 > 0.f ? h21 : 0.f;
        float p = h20*w3v0 + h21*w3v1;
        p += __shfl_xor(p, 1);
        p += __shfl_xor(p, 2);
        p += __shfl_xor(p, 4);
        p += __shfl_xor(p, 8);
        if ((l & 15) == 0){
          int row = mw*64 + mt*16 + (l>>4)*4 + i;
          red[row*4 + nw] = p;
        }
      }
    }
    __syncthreads();
    if (tid < 128){
      int r = rl[tid];
      if (r >= 0){
        float sum = red[tid*4+0] + red[tid*4+1] + red[tid*4+2] + red[tid*4+3] + b3[e];
        eo[(size_t)r*E_N + e] = 1.f/(1.f + expf(-sum));
      }
    }
  }
}

// ---------------------------------------------------------------------------
// AG: final aggregation out[rt*B+row] = w0*eo[i0] + w1*eo[i1].
// ---------------------------------------------------------------------------
__global__ __launch_bounds__(512) void aggregate_kernel(
    const int* __restrict__ selIdx, const float2* __restrict__ selW,
    const float* __restrict__ eo, float* __restrict__ out)
{
  int row = blockIdx.x*512 + threadIdx.x;
#pragma unroll
  for (int rt=0; rt<2; rt++){
    int s = selIdx[rt*B_N + row];
    float2 wv = selW[rt*B_N + row];
    out[(size_t)rt*B_N + row] = wv.x * eo[(size_t)row*E_N + (s&7)]
                              + wv.y * eo[(size_t)row*E_N + ((s>>8)&7)];
  }
}

// ---------------------------------------------------------------------------
extern "C" void kernel_launch(void* const* d_in, const int* in_sizes, int n_in,
                              void* d_out, int out_size, void* d_ws, size_t ws_size,
                              hipStream_t stream){
  const float* text   = (const float*)d_in[0];
  const float* video  = (const float*)d_in[1];
  const float* exp_w1 = (const float*)d_in[2];
  const float* exp_b1 = (const float*)d_in[3];
  const float* exp_w2 = (const float*)d_in[4];
  const float* exp_b2 = (const float*)d_in[5];
  const float* exp_w3 = (const float*)d_in[6];
  const float* exp_b3 = (const float*)d_in[7];
  const float* tw1 = (const float*)d_in[8];
  const float* tb1 = (const float*)d_in[9];
  const float* tw2 = (const float*)d_in[10];
  const float* tb2 = (const float*)d_in[11];
  const float* vw1 = (const float*)d_in[12];
  const float* vb1 = (const float*)d_in[13];
  const float* vw2 = (const float*)d_in[14];
  const float* vb2 = (const float*)d_in[15];
  float* out = (float*)d_out;

  // ws layout (256B-aligned chunks)
  size_t off = 0;
  auto alloc = [&](size_t bytes) -> char* {
    char* p = (char*)d_ws + off;
    off += (bytes + 255) & ~(size_t)255;
    return p;
  };
  int*    counters = (int*)   alloc(16*4);
  int*    flags    = (int*)   alloc((size_t)FLAG_CAP*4);
  int*    selIdx   = (int*)   alloc((size_t)2*B_N*4);
  float2* selW     = (float2*)alloc((size_t)2*B_N*8);
  int*    bucket   = (int*)   alloc((size_t)8*B_N*4);
  float*  eo       = (float*) alloc((size_t)B_N*E_N*4);
  unsigned short* w1b  = (unsigned short*)alloc((size_t)W1E*2);
  unsigned short* w2b  = (unsigned short*)alloc((size_t)W2E*2);
  unsigned short* t_hi = (unsigned short*)alloc((size_t)TRE*2);
  unsigned short* t_lo = (unsigned short*)alloc((size_t)TRE*2);
  unsigned short* v_hi = (unsigned short*)alloc((size_t)VRE*2);
  unsigned short* v_lo = (unsigned short*)alloc((size_t)VRE*2);
  unsigned short* comb = (unsigned short*)alloc((size_t)B_N*D_N*2);  // 160 MB
  const int useComb = (off <= ws_size) ? 1 : 0;

  convert_weights<<<12544, 256, 0, stream>>>(exp_w1, exp_w2, tw1, vw1,
                                             w1b, w2b, t_hi, t_lo, v_hi, v_lo,
                                             counters);
  router_mfma<<<2048, 512, 0, stream>>>(text, video, t_hi, t_lo, v_hi, v_lo,
                                        tb1, tw2, tb2, vb1, vw2, vb2,
                                        selIdx, selW, flags, counters,
                                        comb, useComb);
  router_exact<<<FLAG_CAP, 256, 0, stream>>>(text, video, tw1, tb1, tw2, tb2,
                                             vw1, vb1, vw2, vb2,
                                             selIdx, selW, flags, counters);
  bucket_build<<<256, 256, 0, stream>>>(selIdx, bucket, counters);
  if (useComb){
    expert_sparse<1><<<4096, 512, 0, stream>>>(comb, text, video,
                                               w1b, exp_b1, w2b, exp_b2,
                                               exp_w3, exp_b3, bucket, counters, eo);
  } else {
    expert_sparse<0><<<4096, 512, 0, stream>>>(comb, text, video,
                                               w1b, exp_b1, w2b, exp_b2,
                                               exp_w3, exp_b3, bucket, counters, eo);
  }
  aggregate_kernel<<<128, 512, 0, stream>>>(selIdx, selW, eo, out);
}

// Round 14
// 569.990 us; speedup vs baseline: 1.1267x; 1.0014x over previous
//
#include <hip/hip_runtime.h>
#include <stdint.h>
#include <math.h>

#define B_N 65536
#define H_N 768
#define V_N 512
#define D_N 1280
#define E_N 8
#define N1  256
#define N2  128

#define W1E (E_N*D_N*N1)   // 2621440
#define W2E (E_N*N1*N2)    // 262144
#define TRE (24*16*512)    // 196608  text router W1 tiles
#define VRE (16*16*512)    // 131072  video router W1 tiles

#define DELTA    5e-3f
#define FLAG_CAP 8192

typedef __attribute__((ext_vector_type(8))) short bf16x8;
typedef __attribute__((ext_vector_type(4))) float f32x4;

__device__ __forceinline__ unsigned short f2bf(float f){
  union{float f;uint32_t u;}v; v.f=f;
  uint32_t r = v.u + 0x7FFFu + ((v.u>>16)&1u);
  return (unsigned short)(r>>16);
}
__device__ __forceinline__ float bf2f(unsigned short s){
  union{uint32_t u; float f;}v; v.u = ((uint32_t)s)<<16; return v.f;
}
__device__ __forceinline__ void glds16(const unsigned short* g, unsigned short* l){
  __builtin_amdgcn_global_load_lds(
      (const __attribute__((address_space(1))) void*)g,
      (__attribute__((address_space(3))) void*)l, 16, 0, 0);
}

// ---------------------------------------------------------------------------
// K0: convert expert weights + router W1 (hi/lo split) to MFMA-fragment tiles.
// ---------------------------------------------------------------------------
__global__ void convert_weights(const float* __restrict__ w1,
                                const float* __restrict__ w2,
                                const float* __restrict__ tw1,
                                const float* __restrict__ vw1,
                                unsigned short* __restrict__ w1b,
                                unsigned short* __restrict__ w2b,
                                unsigned short* __restrict__ t_hi,
                                unsigned short* __restrict__ t_lo,
                                unsigned short* __restrict__ v_hi,
                                unsigned short* __restrict__ v_lo,
                                int* __restrict__ counters){
  int i = blockIdx.x*256 + threadIdx.x;
  if (i < 16) counters[i] = 0;   // [0]=flag count, [8..15]=bucket bases
  if (i < W1E){
    int tile = i >> 9, r = i & 511;
    int l = r >> 3, j = r & 7;
    int gt = tile & 15, t2 = tile >> 4;
    int ks = t2 % 40, e = t2 / 40;
    int k = ks*32 + 8*(l>>4) + j;
    int n = gt*16 + (l&15);
    w1b[i] = f2bf(w1[((size_t)e*D_N + k)*N1 + n]);
    return;
  }
  i -= W1E;
  if (i < W2E){
    int tile = i >> 9, r = i & 511;
    int l = r >> 3, j = r & 7;
    int ft = tile & 7, t2 = tile >> 3;
    int ks = t2 & 7, e = t2 >> 3;
    int k = ks*32 + 8*(l>>4) + j;
    int f = ft*16 + (l&15);
    w2b[i] = f2bf(w2[((size_t)e*N1 + k)*N2 + f]);
    return;
  }
  i -= W2E;
  if (i < TRE){
    int tile = i >> 9, r = i & 511;
    int l = r >> 3, j = r & 7;
    int gt = tile & 15, ks = tile >> 4;
    int k = ks*32 + 8*(l>>4) + j;
    int n = gt*16 + (l&15);
    float x = tw1[(size_t)k*N1 + n];
    unsigned short h = f2bf(x);
    t_hi[i] = h;
    t_lo[i] = f2bf(x - bf2f(h));
    return;
  }
  i -= TRE;
  if (i < VRE){
    int tile = i >> 9, r = i & 511;
    int l = r >> 3, j = r & 7;
    int gt = tile & 15, ks = tile >> 4;
    int k = ks*32 + 8*(l>>4) + j;
    int n = gt*16 + (l&15);
    float x = vw1[(size_t)k*N1 + n];
    unsigned short h = f2bf(x);
    v_hi[i] = h;
    v_lo[i] = f2bf(x - bf2f(h));
  }
}

// ---------------------------------------------------------------------------
// R1: MFMA router, 2-TERM split: L ~= x_hi*(W_hi + W_lo) (= x_hi*W exactly).
// One barrier per K-step, A hi-only double-buffer. Near-tie rows
// (gap23 < DELTA=5e-3 ~= 6.7 sigma of the dropped-term error) flagged for
// exact f64 recheck. Also writes bf16 'combined' rows for expert_sparse<1>.
// ---------------------------------------------------------------------------
__global__ __launch_bounds__(512,4) void router_mfma(
    const float* __restrict__ text, const float* __restrict__ video,
    const unsigned short* __restrict__ t_hi, const unsigned short* __restrict__ t_lo,
    const unsigned short* __restrict__ v_hi, const unsigned short* __restrict__ v_lo,
    const float* __restrict__ tb1, const float* __restrict__ tw2, const float* __restrict__ tb2,
    const float* __restrict__ vb1, const float* __restrict__ vw2, const float* __restrict__ vb2,
    int* __restrict__ selIdx, float2* __restrict__ selW,
    int* __restrict__ flags, int* __restrict__ counters,
    unsigned short* __restrict__ comb, int writeComb)
{
  __shared__ union {
    unsigned short a[2*2560];     // hi A double-buffer
    float h[64*264];
  } s;
  __shared__ float W2s[256*8];

  const int tid = threadIdx.x;
  const int rt = blockIdx.x >> 10;
  const int r0 = (blockIdx.x & 1023) * 64;
  const float* X = rt ? video : text;
  const unsigned short* Whi = rt ? v_hi : t_hi;
  const unsigned short* Wlo = rt ? v_lo : t_lo;
  const float* b1 = rt ? vb1 : tb1;
  const float* W2 = rt ? vw2 : tw2;
  const float* b2 = rt ? vb2 : tb2;
  const int K  = rt ? V_N : H_N;
  const int NK = K >> 5;
  const int cbase = rt ? H_N : 0;

  const int w = tid >> 6, l = tid & 63;
  const int mw = w & 1, nw = w >> 1;
  const int srow = tid >> 3, skq = (tid & 7) * 4;

  for (int i = tid; i < 2048; i += 512) W2s[i] = W2[i];

  f32x4 acc[2][4];
#pragma unroll
  for (int a=0;a<2;a++)
#pragma unroll
    for (int b=0;b<4;b++) acc[a][b] = (f32x4){0.f,0.f,0.f,0.f};

  const float* xrow = X + (size_t)(r0 + srow)*K + skq;
  float4 areg = *(const float4*)xrow;

  for (int ks = 0; ks < NK; ++ks){
    {
      unsigned short* dhi = s.a + (ks&1)*2560 + srow*40 + skq;
      ushort4 uh;
      uh.x = f2bf(areg.x);
      uh.y = f2bf(areg.y);
      uh.z = f2bf(areg.z);
      uh.w = f2bf(areg.w);
      *(ushort4*)dhi = uh;
      if (writeComb)
        *(ushort4*)(comb + (size_t)(r0+srow)*D_N + cbase + ks*32 + skq) = uh;
    }
    if (ks + 1 < NK) areg = *(const float4*)(xrow + (ks+1)*32);
    __syncthreads();   // buf[ks&1] staged; next iter stages the OTHER buf

    bf16x8 bh[4], bl[4];
#pragma unroll
    for (int nt=0;nt<4;nt++){
      size_t off = (size_t)(ks*16 + nw*4 + nt)*512 + l*8;
      bh[nt] = *(const bf16x8*)(Whi + off);
      bl[nt] = *(const bf16x8*)(Wlo + off);
    }
    bf16x8 ah[2];
    const unsigned short* ahi = s.a + (ks&1)*2560;
#pragma unroll
    for (int mt=0;mt<2;mt++){
      int ro = (mw*32 + mt*16 + (l&15))*40 + 8*(l>>4);
      ah[mt] = *(const bf16x8*)(ahi + ro);
    }
#pragma unroll
    for (int mt=0;mt<2;mt++)
#pragma unroll
      for (int nt=0;nt<4;nt++){
        acc[mt][nt] = __builtin_amdgcn_mfma_f32_16x16x32_bf16(ah[mt], bh[nt], acc[mt][nt], 0,0,0);
        acc[mt][nt] = __builtin_amdgcn_mfma_f32_16x16x32_bf16(ah[mt], bl[nt], acc[mt][nt], 0,0,0);
      }
  }
  __syncthreads();   // all ah reads done before s.h overlays the union

#pragma unroll
  for (int mt=0;mt<2;mt++){
#pragma unroll
    for (int nt=0;nt<4;nt++){
      int n = nw*64 + nt*16 + (l&15);
      float b1v = b1[n];
#pragma unroll
      for (int i=0;i<4;i++){
        int row = mw*32 + mt*16 + (l>>4)*4 + i;
        float v = acc[mt][nt][i] + b1v;
        s.h[row*264 + n] = v > 0.f ? v : 0.f;
      }
    }
  }
  __syncthreads();

  {
    const int r = tid >> 3, j = tid & 7;
    float part[8];
#pragma unroll
    for (int e=0;e<8;e++) part[e] = 0.f;
    for (int q=0;q<32;q++){
      int n = j + 8*q;
      float hv = s.h[r*264 + n];
#pragma unroll
      for (int e=0;e<8;e++) part[e] += hv * W2s[n*8 + e];
    }
#pragma unroll
    for (int m=1;m<=4;m<<=1)
#pragma unroll
      for (int e=0;e<8;e++) part[e] += __shfl_xor(part[e], m);

    if (j == 0){
      int row = r0 + r;
      float L[8];
#pragma unroll
      for (int e=0;e<8;e++) L[e] = part[e] + b2[e];
      int i0 = 0; float v0 = L[0];
#pragma unroll
      for (int e=1;e<8;e++) if (L[e] > v0){ v0 = L[e]; i0 = e; }
      int i1 = -1; float v1 = -1e30f;
#pragma unroll
      for (int e=0;e<8;e++) if (e != i0 && L[e] > v1){ v1 = L[e]; i1 = e; }
      float v2 = -1e30f;
#pragma unroll
      for (int e=0;e<8;e++) if (e != i0 && e != i1 && L[e] > v2) v2 = L[e];
      if (v1 - v2 < DELTA){
        int idx = atomicAdd(&counters[0], 1);
        if (idx < FLAG_CAP) flags[idx] = (rt<<16) | row;
      }
      float e1 = expf(v1 - v0);
      float invd = 1.f/(1.f + e1);
      selIdx[rt*B_N + row] = i0 | (i1 << 8);
      selW[rt*B_N + row] = make_float2(invd, e1*invd);
    }
  }
}

// ---------------------------------------------------------------------------
// R2: exact f64 router for flagged near-tie rows -> overwrite selIdx/selW.
// 4 independent f64 accumulators break the serial FMA chain (4x ILP).
// ---------------------------------------------------------------------------
__global__ __launch_bounds__(256) void router_exact(
    const float* __restrict__ text, const float* __restrict__ video,
    const float* __restrict__ tw1, const float* __restrict__ tb1,
    const float* __restrict__ tw2, const float* __restrict__ tb2,
    const float* __restrict__ vw1, const float* __restrict__ vb1,
    const float* __restrict__ vw2, const float* __restrict__ vb2,
    int* __restrict__ selIdx, float2* __restrict__ selW,
    const int* __restrict__ flags, const int* __restrict__ counters)
{
  int nf = counters[0]; if (nf > FLAG_CAP) nf = FLAG_CAP;
  if ((int)blockIdx.x >= nf) return;
  int code = flags[blockIdx.x];
  int rt = code >> 16, row = code & 0xFFFF;
  const float* X  = rt ? video : text;
  const float* W1 = rt ? vw1 : tw1;
  const float* b1 = rt ? vb1 : tb1;
  const float* W2 = rt ? vw2 : tw2;
  const float* b2 = rt ? vb2 : tb2;
  const int K = rt ? V_N : H_N;

  __shared__ float xs[H_N];
  __shared__ double red[4][8];
  const int tid = threadIdx.x;
  for (int k = tid; k < K; k += 256) xs[k] = X[(size_t)row*K + k];
  __syncthreads();

  double a0 = 0.0, a1 = 0.0, a2 = 0.0, a3 = 0.0;
  for (int k = 0; k < K; k += 4){
    a0 += (double)xs[k+0] * (double)W1[(size_t)(k+0)*N1 + tid];
    a1 += (double)xs[k+1] * (double)W1[(size_t)(k+1)*N1 + tid];
    a2 += (double)xs[k+2] * (double)W1[(size_t)(k+2)*N1 + tid];
    a3 += (double)xs[k+3] * (double)W1[(size_t)(k+3)*N1 + tid];
  }
  double sAcc = ((a0 + a1) + (a2 + a3)) + (double)b1[tid];
  double h = sAcc > 0.0 ? sAcc : 0.0;

  double p[8];
#pragma unroll
  for (int e=0;e<8;e++) p[e] = h * (double)W2[tid*8 + e];
#pragma unroll
  for (int m=1;m<=32;m<<=1)
#pragma unroll
    for (int e=0;e<8;e++) p[e] += __shfl_xor(p[e], m);
  if ((tid & 63) == 0){
#pragma unroll
    for (int e=0;e<8;e++) red[tid>>6][e] = p[e];
  }
  __syncthreads();
  if (tid == 0){
    double L[8];
#pragma unroll
    for (int e=0;e<8;e++) L[e] = red[0][e]+red[1][e]+red[2][e]+red[3][e] + (double)b2[e];
    int i0 = 0; double v0 = L[0];
#pragma unroll
    for (int e=1;e<8;e++) if (L[e] > v0){ v0 = L[e]; i0 = e; }
    int i1 = -1; double v1 = -1e300;
#pragma unroll
    for (int e=0;e<8;e++) if (e != i0 && L[e] > v1){ v1 = L[e]; i1 = e; }
    double e1 = exp(v1 - v0);
    double invd = 1.0/(1.0 + e1);
    selIdx[rt*B_N + row] = i0 | (i1 << 8);
    selW[rt*B_N + row] = make_float2((float)invd, (float)(e1*invd));
  }
}

// ---------------------------------------------------------------------------
// BB: build per-expert row buckets (single-kernel block-aggregated atomics).
// ---------------------------------------------------------------------------
__global__ __launch_bounds__(256) void bucket_build(
    const int* __restrict__ selIdx, int* __restrict__ bucket,
    int* __restrict__ counters)
{
  __shared__ int lcnt[8], lbase[8], lpos[8];
  const int tid = threadIdx.x;
  const int row = blockIdx.x*256 + tid;
  if (tid < 8){ lcnt[tid] = 0; lpos[tid] = 0; }
  __syncthreads();
  int st = selIdx[row], sv = selIdx[B_N + row];
  int mask = (1<<(st&7)) | (1<<((st>>8)&7)) | (1<<(sv&7)) | (1<<((sv>>8)&7));
#pragma unroll
  for (int e=0;e<8;e++) if ((mask>>e)&1) atomicAdd(&lcnt[e], 1);
  __syncthreads();
  if (tid < 8) lbase[tid] = atomicAdd(&counters[8+tid], lcnt[tid]);
  __syncthreads();
#pragma unroll
  for (int e=0;e<8;e++)
    if ((mask>>e)&1){
      int p = atomicAdd(&lpos[e], 1);
      bucket[e*B_N + lbase[e] + p] = row;
    }
}

// ---------------------------------------------------------------------------
// K1: sparse expert MLP (round-10 structure) with AGPR CAP: the GEMM2
// accumulator REUSES acc[mt][0..1] (no separate acc2) so AGPR high-water is
// exactly 64 -> total regs 128 -> 4 waves/SIMD -> 2 blocks/CU.
// BF16A=1: A (gathered) + B (contiguous w1b chunk) staged per K-step via
// global_load_lds into a 24 KB buffer, double-buffered; one barrier/K-step.
// BF16A=0: round-4 f32 staged fallback.
// ---------------------------------------------------------------------------
template<int BF16A>
__global__ __launch_bounds__(512,4) void expert_sparse(
    const unsigned short* __restrict__ comb,
    const float* __restrict__ text, const float* __restrict__ video,
    const unsigned short* __restrict__ w1b, const float* __restrict__ b1,
    const unsigned short* __restrict__ w2b, const float* __restrict__ b2,
    const float* __restrict__ w3, const float* __restrict__ b3,
    const int* __restrict__ bucket, const int* __restrict__ counters,
    float* __restrict__ eo)
{
  __shared__ __align__(16) unsigned short shr[32768];   // 64 KB union
  __shared__ int rl[128];

  unsigned short* As  = shr;
  unsigned short* h1s = shr;

  const int tid = threadIdx.x;
  const int e = blockIdx.x & 7;          // expert <-> XCD affinity
  const int t = blockIdx.x >> 3;
  const int n_e = counters[8 + e];
  if (t*128 >= n_e) return;

  if (tid < 128){
    int idx = t*128 + tid;
    rl[tid] = (idx < n_e) ? bucket[e*B_N + idx] : -1;
  }
  __syncthreads();

  const int w = tid >> 6, l = tid & 63;
  const int mw = w & 1, nw = w >> 1;

  f32x4 acc[4][4];
#pragma unroll
  for (int a=0;a<4;a++)
#pragma unroll
    for (int b=0;b<4;b++) acc[a][b] = (f32x4){0.f,0.f,0.f,0.f};

  const unsigned short* w1e = w1b + (size_t)e*40*16*512;

  if constexpr (BF16A){
    int rr = rl[w*16 + (l&15)]; if (rr < 0) rr = 0;
    const unsigned short* gsA = comb + (size_t)rr*D_N + 8*(l>>4);

    {
      unsigned short* b0 = As;
      glds16(gsA, b0 + w*512);
      glds16(w1e + (size_t)(0*512 + w*64 + l)*8, b0 + 4096 + (0*512 + w*64)*8);
      glds16(w1e + (size_t)(1*512 + w*64 + l)*8, b0 + 4096 + (1*512 + w*64)*8);
    }

    for (int ks = 0; ks < 40; ++ks){
      __syncthreads();
      if (ks + 1 < 40){
        unsigned short* nb = As + (((ks+1)&1) ? 12288 : 0);
        const unsigned short* srcB = w1e + (size_t)(ks+1)*8192;
        glds16(gsA + (ks+1)*32, nb + w*512);
        glds16(srcB + (size_t)(0*512 + w*64 + l)*8, nb + 4096 + (0*512 + w*64)*8);
        glds16(srcB + (size_t)(1*512 + w*64 + l)*8, nb + 4096 + (1*512 + w*64)*8);
      }
      const unsigned short* Acur = As + (ks&1)*12288;
      const unsigned short* Bcur = Acur + 4096;
      bf16x8 af[4], bf[4];
#pragma unroll
      for (int mt=0;mt<4;mt++)
        af[mt] = *(const bf16x8*)(Acur + (mw*4+mt)*512 + l*8);
#pragma unroll
      for (int nt=0;nt<4;nt++)
        bf[nt] = *(const bf16x8*)(Bcur + (nw*4+nt)*512 + l*8);
#pragma unroll
      for (int mt=0;mt<4;mt++)
#pragma unroll
        for (int nt=0;nt<4;nt++)
          acc[mt][nt] = __builtin_amdgcn_mfma_f32_16x16x32_bf16(af[mt], bf[nt], acc[mt][nt], 0,0,0);
    }
    __syncthreads();
  } else {
    const int sridx = rl[(tid>>6)*16 + (l&15)];
    const int srr = sridx < 0 ? 0 : sridx;
    const float* tb = text  + (size_t)srr*H_N + (l>>4)*8;
    const float* vb = video + (size_t)srr*V_N + (l>>4)*8;
    float4 fa0 = *(const float4*)tb;
    float4 fa1 = *(const float4*)(tb + 4);

    bf16x8 bfc[4];
#pragma unroll
    for (int nt=0;nt<4;nt++)
      bfc[nt] = *(const bf16x8*)(w1e + (size_t)(nw*4 + nt)*512 + l*8);

    for (int ks = 0; ks < 40; ++ks){
      {
        union { bf16x8 v; unsigned short u[8]; } sw;
        sw.u[0]=f2bf(fa0.x); sw.u[1]=f2bf(fa0.y); sw.u[2]=f2bf(fa0.z); sw.u[3]=f2bf(fa0.w);
        sw.u[4]=f2bf(fa1.x); sw.u[5]=f2bf(fa1.y); sw.u[6]=f2bf(fa1.z); sw.u[7]=f2bf(fa1.w);
        *(bf16x8*)(As + tid*8) = sw.v;
      }
      if (ks < 39){
        int k0 = (ks+1)*32;
        const float* p = (k0 < H_N) ? (tb + k0) : (vb + (k0 - H_N));
        fa0 = *(const float4*)p;
        fa1 = *(const float4*)(p + 4);
      }
      __syncthreads();

      bf16x8 af[4];
#pragma unroll
      for (int mt=0;mt<4;mt++)
        af[mt] = *(const bf16x8*)(As + (mw*4+mt)*512 + l*8);

      bf16x8 bfn[4];
      if (ks < 39){
#pragma unroll
        for (int nt=0;nt<4;nt++)
          bfn[nt] = *(const bf16x8*)(w1e + (size_t)((ks+1)*16 + nw*4 + nt)*512 + l*8);
      }
#pragma unroll
      for (int mt=0;mt<4;mt++)
#pragma unroll
        for (int nt=0;nt<4;nt++)
          acc[mt][nt] = __builtin_amdgcn_mfma_f32_16x16x32_bf16(af[mt], bfc[nt], acc[mt][nt], 0,0,0);
      if (ks < 39){
#pragma unroll
        for (int nt=0;nt<4;nt++) bfc[nt] = bfn[nt];
      }
      __syncthreads();
    }
  }

  // epilogue 1: h1 = relu(acc + b1) -> h1s fragment tiles (GEMM2 A-operand)
#pragma unroll
  for (int mt=0;mt<4;mt++){
#pragma unroll
    for (int nt=0;nt<4;nt++){
      int n = nw*64 + nt*16 + (l&15);
      float b1v = b1[e*N1 + n];
      int tile = (mw*4+mt)*8 + (n>>5);
      int sub  = 16*((n>>3)&3);
      int jj   = n & 7;
#pragma unroll
      for (int i=0;i<4;i++){
        int r15 = (l>>4)*4 + i;
        float v = acc[mt][nt][i] + b1v;
        v = v > 0.f ? v : 0.f;
        h1s[tile*512 + (r15 + sub)*8 + jj] = f2bf(v);
      }
    }
  }
  __syncthreads();

  // GEMM2: 128x128, K=256 from h1s frag tiles; B (w2b tiles) from global.
  // Accumulator REUSES acc[mt][0..1] (AGPR high-water stays 64).
#pragma unroll
  for (int mt=0;mt<4;mt++)
#pragma unroll
    for (int ft=0;ft<2;ft++) acc[mt][ft] = (f32x4){0.f,0.f,0.f,0.f};
  const unsigned short* w2e = w2b + (size_t)e*8*8*512;
#pragma unroll
  for (int ks2=0; ks2<8; ++ks2){
    bf16x8 af2[4], bf2v[2];
#pragma unroll
    for (int mt=0;mt<4;mt++)
      af2[mt] = *(const bf16x8*)(h1s + ((mw*4+mt)*8 + ks2)*512 + l*8);
#pragma unroll
    for (int ft=0;ft<2;ft++)
      bf2v[ft] = *(const bf16x8*)(w2e + (size_t)(ks2*8 + nw*2 + ft)*512 + l*8);
#pragma unroll
    for (int mt=0;mt<4;mt++)
#pragma unroll
      for (int ft=0;ft<2;ft++)
        acc[mt][ft] = __builtin_amdgcn_mfma_f32_16x16x32_bf16(af2[mt], bf2v[ft], acc[mt][ft], 0,0,0);
  }
  __syncthreads();

  // GEMM3 in registers: h2 = relu(acc + b2), dot with w3, 16-lane reduce.
  {
    const float* w3e = w3 + e*N2;
    const float* b2e = b2 + e*N2;
    const int f0 = nw*32 + (l&15);
    const int f1 = f0 + 16;
    float w3v0 = w3e[f0], w3v1 = w3e[f1];
    float b2v0 = b2e[f0], b2v1 = b2e[f1];
    float* red = (float*)shr;
#pragma unroll
    for (int mt=0;mt<4;mt++){
#pragma unroll
      for (int i=0;i<4;i++){
        float h20 = acc[mt][0][i] + b2v0; h20 = h20 > 0.f ? h20 : 0.f;
        float h21 = acc[mt][1][i] + b2v1; h21 = h21 > 0.f ? h21 : 0.f;
        float p = h20*w3v0 + h21*w3v1;
        p += __shfl_xor(p, 1);
        p += __shfl_xor(p, 2);
        p += __shfl_xor(p, 4);
        p += __shfl_xor(p, 8);
        if ((l & 15) == 0){
          int row = mw*64 + mt*16 + (l>>4)*4 + i;
          red[row*4 + nw] = p;
        }
      }
    }
    __syncthreads();
    if (tid < 128){
      int r = rl[tid];
      if (r >= 0){
        float sum = red[tid*4+0] + red[tid*4+1] + red[tid*4+2] + red[tid*4+3] + b3[e];
        eo[(size_t)r*E_N + e] = 1.f/(1.f + expf(-sum));
      }
    }
  }
}

// ---------------------------------------------------------------------------
// AG: final aggregation out[rt*B+row] = w0*eo[i0] + w1*eo[i1].
// ---------------------------------------------------------------------------
__global__ __launch_bounds__(512) void aggregate_kernel(
    const int* __restrict__ selIdx, const float2* __restrict__ selW,
    const float* __restrict__ eo, float* __restrict__ out)
{
  int row = blockIdx.x*512 + threadIdx.x;
#pragma unroll
  for (int rt=0; rt<2; rt++){
    int s = selIdx[rt*B_N + row];
    float2 wv = selW[rt*B_N + row];
    out[(size_t)rt*B_N + row] = wv.x * eo[(size_t)row*E_N + (s&7)]
                              + wv.y * eo[(size_t)row*E_N + ((s>>8)&7)];
  }
}

// ---------------------------------------------------------------------------
extern "C" void kernel_launch(void* const* d_in, const int* in_sizes, int n_in,
                              void* d_out, int out_size, void* d_ws, size_t ws_size,
                              hipStream_t stream){
  const float* text   = (const float*)d_in[0];
  const float* video  = (const float*)d_in[1];
  const float* exp_w1 = (const float*)d_in[2];
  const float* exp_b1 = (const float*)d_in[3];
  const float* exp_w2 = (const float*)d_in[4];
  const float* exp_b2 = (const float*)d_in[5];
  const float* exp_w3 = (const float*)d_in[6];
  const float* exp_b3 = (const float*)d_in[7];
  const float* tw1 = (const float*)d_in[8];
  const float* tb1 = (const float*)d_in[9];
  const float* tw2 = (const float*)d_in[10];
  const float* tb2 = (const float*)d_in[11];
  const float* vw1 = (const float*)d_in[12];
  const float* vb1 = (const float*)d_in[13];
  const float* vw2 = (const float*)d_in[14];
  const float* vb2 = (const float*)d_in[15];
  float* out = (float*)d_out;

  // ws layout (256B-aligned chunks)
  size_t off = 0;
  auto alloc = [&](size_t bytes) -> char* {
    char* p = (char*)d_ws + off;
    off += (bytes + 255) & ~(size_t)255;
    return p;
  };
  int*    counters = (int*)   alloc(16*4);
  int*    flags    = (int*)   alloc((size_t)FLAG_CAP*4);
  int*    selIdx   = (int*)   alloc((size_t)2*B_N*4);
  float2* selW     = (float2*)alloc((size_t)2*B_N*8);
  int*    bucket   = (int*)   alloc((size_t)8*B_N*4);
  float*  eo       = (float*) alloc((size_t)B_N*E_N*4);
  unsigned short* w1b  = (unsigned short*)alloc((size_t)W1E*2);
  unsigned short* w2b  = (unsigned short*)alloc((size_t)W2E*2);
  unsigned short* t_hi = (unsigned short*)alloc((size_t)TRE*2);
  unsigned short* t_lo = (unsigned short*)alloc((size_t)TRE*2);
  unsigned short* v_hi = (unsigned short*)alloc((size_t)VRE*2);
  unsigned short* v_lo = (unsigned short*)alloc((size_t)VRE*2);
  unsigned short* comb = (unsigned short*)alloc((size_t)B_N*D_N*2);  // 160 MB
  const int useComb = (off <= ws_size) ? 1 : 0;

  convert_weights<<<12544, 256, 0, stream>>>(exp_w1, exp_w2, tw1, vw1,
                                             w1b, w2b, t_hi, t_lo, v_hi, v_lo,
                                             counters);
  router_mfma<<<2048, 512, 0, stream>>>(text, video, t_hi, t_lo, v_hi, v_lo,
                                        tb1, tw2, tb2, vb1, vw2, vb2,
                                        selIdx, selW, flags, counters,
                                        comb, useComb);
  router_exact<<<FLAG_CAP, 256, 0, stream>>>(text, video, tw1, tb1, tw2, tb2,
                                             vw1, vb1, vw2, vb2,
                                             selIdx, selW, flags, counters);
  bucket_build<<<256, 256, 0, stream>>>(selIdx, bucket, counters);
  if (useComb){
    expert_sparse<1><<<4096, 512, 0, stream>>>(comb, text, video,
                                               w1b, exp_b1, w2b, exp_b2,
                                               exp_w3, exp_b3, bucket, counters, eo);
  } else {
    expert_sparse<0><<<4096, 512, 0, stream>>>(comb, text, video,
                                               w1b, exp_b1, w2b, exp_b2,
                                               exp_w3, exp_b3, bucket, counters, eo);
  }
  aggregate_kernel<<<128, 512, 0, stream>>>(selIdx, selW, eo, out);
}